// Round 5
// baseline (1054.201 us; speedup 1.0000x reference)
//
#include <hip/hip_runtime.h>
#include <hip/hip_bf16.h>

#define GG 128   // num_graphs (static in problem)

// ---------------- bf16 helpers (RNE) ----------------
__device__ __forceinline__ ushort f2bf(float f) {
    union { float f; unsigned u; } v; v.f = f;
    unsigned r = v.u + 0x7FFF + ((v.u >> 16) & 1);
    return (ushort)(r >> 16);
}
__device__ __forceinline__ float bf2f(ushort s) {
    union { unsigned u; float f; } v; v.u = ((unsigned)s) << 16;
    return v.f;
}

// ---------------- f32 -> bf16 convert (vectorized) ----------------
__global__ __launch_bounds__(256) void to_bf16(const float* __restrict__ X,
                                               ushort* __restrict__ Xb, int n4) {
    int i = blockIdx.x * 256 + threadIdx.x;
    if (i >= n4) return;
    float4 v = reinterpret_cast<const float4*>(X)[i];
    ushort4 o;
    o.x = f2bf(v.x); o.y = f2bf(v.y); o.z = f2bf(v.z); o.w = f2bf(v.w);
    reinterpret_cast<ushort4*>(Xb)[i] = o;
}

// ------------- degrees + ranks, 4-replica split (returning atomics) --------
__global__ __launch_bounds__(256) void deg_rank(const int* __restrict__ ei,
                                                int* __restrict__ degfR,
                                                int* __restrict__ degbR,
                                                int* __restrict__ rankf,
                                                int* __restrict__ rankb,
                                                int e, int n) {
    int i = blockIdx.x * 256 + threadIdx.x;
    if (i >= e) return;
    int s = ei[i], d = ei[e + i];
    int r = i & 3;
    rankf[i] = atomicAdd(degfR + (size_t)r * n + d, 1);
    rankb[i] = atomicAdd(degbR + (size_t)r * n + s, 1);
}

// ------------- sum replicas -> full degrees ---------------------------------
__global__ __launch_bounds__(256) void sum_reps(const int* __restrict__ degfR,
                                                const int* __restrict__ degbR,
                                                int* __restrict__ degf,
                                                int* __restrict__ degb, int n) {
    int i = blockIdx.x * 256 + threadIdx.x;
    if (i >= n) return;
    degf[i] = degfR[i] + degfR[n + i] + degfR[2 * (size_t)n + i] + degfR[3 * (size_t)n + i];
    degb[i] = degbR[i] + degbR[n + i] + degbR[2 * (size_t)n + i] + degbR[3 * (size_t)n + i];
}

// ---------------- 3-phase exclusive scan (f and b via blockIdx.y) -----------
__global__ __launch_bounds__(256) void scan1(const int* __restrict__ degf,
                                             const int* __restrict__ degb,
                                             int* __restrict__ part_f,
                                             int* __restrict__ part_b, int n) {
    const int* deg = blockIdx.y ? degb : degf;
    int* partial = blockIdx.y ? part_b : part_f;
    __shared__ int s[256];
    int t = threadIdx.x, i = blockIdx.x * 256 + t;
    s[t] = (i < n) ? deg[i] : 0;
    __syncthreads();
    for (int o = 128; o > 0; o >>= 1) {
        if (t < o) s[t] += s[t + o];
        __syncthreads();
    }
    if (t == 0) partial[blockIdx.x] = s[0];
}

__global__ __launch_bounds__(512) void scan2(int* __restrict__ part_f,
                                             int* __restrict__ part_b, int nb) {
    int* partial = blockIdx.x ? part_b : part_f;
    __shared__ int s[512];
    int t = threadIdx.x;
    int v = (t < nb) ? partial[t] : 0;
    s[t] = v;
    __syncthreads();
    for (int o = 1; o < 512; o <<= 1) {
        int u = (t >= o) ? s[t - o] : 0;
        __syncthreads();
        s[t] += u;
        __syncthreads();
    }
    if (t < nb) partial[t] = s[t] - v;  // exclusive
}

__global__ __launch_bounds__(256) void scan3(const int* __restrict__ degf,
                                             const int* __restrict__ degb,
                                             const int* __restrict__ part_f,
                                             const int* __restrict__ part_b,
                                             int* __restrict__ off_f,
                                             int* __restrict__ off_b,
                                             float* __restrict__ invf,
                                             float* __restrict__ invb,
                                             int n, int e) {
    const int* deg = blockIdx.y ? degb : degf;
    const int* partial = blockIdx.y ? part_b : part_f;
    int* off = blockIdx.y ? off_b : off_f;
    float* inv = blockIdx.y ? invb : invf;
    __shared__ int s[256];
    int t = threadIdx.x, i = blockIdx.x * 256 + t;
    int v = (i < n) ? deg[i] : 0;
    s[t] = v;
    __syncthreads();
    for (int o = 1; o < 256; o <<= 1) {
        int u = (t >= o) ? s[t - o] : 0;
        __syncthreads();
        s[t] += u;
        __syncthreads();
    }
    if (i < n) {
        off[i] = partial[blockIdx.x] + s[t] - v;
        inv[i] = 1.f / fmaxf((float)v, 1.f);
    }
    if (i == n - 1) off[n] = e;
}

// ------------- per-node int4 base = off + replica prefix --------------------
__global__ __launch_bounds__(256) void make_base(const int* __restrict__ degfR,
                                                 const int* __restrict__ degbR,
                                                 const int* __restrict__ off_f,
                                                 const int* __restrict__ off_b,
                                                 int4* __restrict__ baseF,
                                                 int4* __restrict__ baseB, int n) {
    int i = blockIdx.x * 256 + threadIdx.x;
    if (i >= n) return;
    {
        int o = off_f[i];
        int c0 = degfR[i], c1 = degfR[n + i], c2 = degfR[2 * (size_t)n + i];
        baseF[i] = make_int4(o, o + c0, o + c0 + c1, o + c0 + c1 + c2);
    }
    {
        int o = off_b[i];
        int c0 = degbR[i], c1 = degbR[n + i], c2 = degbR[2 * (size_t)n + i];
        baseB[i] = make_int4(o, o + c0, o + c0 + c1, o + c0 + c1 + c2);
    }
}

// ---------------- CSR fill: atomic-free scattered stores --------------------
__global__ __launch_bounds__(256) void fill_csr(const int* __restrict__ ei,
                                                const int4* __restrict__ baseF,
                                                const int4* __restrict__ baseB,
                                                const int* __restrict__ rankf,
                                                const int* __restrict__ rankb,
                                                int* __restrict__ csr_f,
                                                int* __restrict__ csr_b, int e) {
    int i = blockIdx.x * 256 + threadIdx.x;
    if (i >= e) return;
    int s = ei[i], d = ei[e + i];
    int r = i & 3;
    int4 bf = baseF[d];
    int4 bb = baseB[s];
    int basef = (r < 2) ? (r == 0 ? bf.x : bf.y) : (r == 2 ? bf.z : bf.w);
    int baseb = (r < 2) ? (r == 0 ? bb.x : bb.y) : (r == 2 ? bb.z : bb.w);
    csr_f[basef + rankf[i]] = s;
    csr_b[baseb + rankb[i]] = d;
}

// ---------- gather-mean from bf16 rows, 32 threads/node (16/dir) ------------
__global__ __launch_bounds__(256) void gather_mean_bf(
    const ushort* __restrict__ Xb,
    const int* __restrict__ off_f, const int* __restrict__ csr_f,
    const float* __restrict__ invf,
    const int* __restrict__ off_b, const int* __restrict__ csr_b,
    const float* __restrict__ invb,
    ushort* __restrict__ aggf, ushort* __restrict__ aggb, int n) {
    int tid = blockIdx.x * 256 + threadIdx.x;
    int node = tid >> 5;
    if (node >= n) return;
    int dir = (tid >> 4) & 1;
    int c = (tid & 15) * 4;
    const int* off = dir ? off_b : off_f;
    const int* csr = dir ? csr_b : csr_f;
    const float* inv = dir ? invb : invf;
    ushort* agg = dir ? aggb : aggf;

    int b = off[node], en = off[node + 1];
    float ax = 0.f, ay = 0.f, az = 0.f, aw = 0.f;
    int k = b;
    for (; k + 3 < en; k += 4) {
        int n0 = csr[k], n1 = csr[k + 1], n2 = csr[k + 2], n3 = csr[k + 3];
        ushort4 v0 = *reinterpret_cast<const ushort4*>(Xb + (size_t)n0 * 64 + c);
        ushort4 v1 = *reinterpret_cast<const ushort4*>(Xb + (size_t)n1 * 64 + c);
        ushort4 v2 = *reinterpret_cast<const ushort4*>(Xb + (size_t)n2 * 64 + c);
        ushort4 v3 = *reinterpret_cast<const ushort4*>(Xb + (size_t)n3 * 64 + c);
        ax += bf2f(v0.x) + bf2f(v1.x) + bf2f(v2.x) + bf2f(v3.x);
        ay += bf2f(v0.y) + bf2f(v1.y) + bf2f(v2.y) + bf2f(v3.y);
        az += bf2f(v0.z) + bf2f(v1.z) + bf2f(v2.z) + bf2f(v3.z);
        aw += bf2f(v0.w) + bf2f(v1.w) + bf2f(v2.w) + bf2f(v3.w);
    }
    for (; k < en; k++) {
        int s = csr[k];
        ushort4 v = *reinterpret_cast<const ushort4*>(Xb + (size_t)s * 64 + c);
        ax += bf2f(v.x); ay += bf2f(v.y); az += bf2f(v.z); aw += bf2f(v.w);
    }
    float iv = inv[node];
    ushort4 r;
    r.x = f2bf(ax * iv); r.y = f2bf(ay * iv); r.z = f2bf(az * iv); r.w = f2bf(aw * iv);
    *reinterpret_cast<ushort4*>(agg + (size_t)node * 64 + c) = r;
}

// ---------------- fused bidirectional SAGE layer (bf16 tiles) ---------------
// out_bf16 = relu(0.5*(mean_f@Wlf^T + mean_b@Wlb^T + x@(Wrf+Wrb)^T + blf+blb))
// pass2 source: Xf (f32) if non-null, else Xb16 (bf16).
__global__ __launch_bounds__(256) void fused_sage(
    const float* __restrict__ Xf, const ushort* __restrict__ Xb16,
    const ushort* __restrict__ aggf, const ushort* __restrict__ aggb,
    const float* __restrict__ Wlf, const float* __restrict__ blf,
    const float* __restrict__ Wrf,
    const float* __restrict__ Wlb, const float* __restrict__ blb,
    const float* __restrict__ Wrb,
    ushort* __restrict__ Out, int n)
{
    __shared__ float sIn[64][68];
    __shared__ float sW[64][68];
    const int t = threadIdx.x;
    const int base = blockIdx.x * 64;
    const int jg = t & 15;
    const int ng = t >> 4;

    float acc[4][4];
#pragma unroll
    for (int a = 0; a < 4; a++)
#pragma unroll
        for (int b = 0; b < 4; b++) acc[a][b] = 0.f;

    for (int p = 0; p < 3; p++) {
        // weights
#pragma unroll
        for (int i = 0; i < 4; i++) {
            int f4 = t + 256 * i;
            int row = f4 >> 4, c4 = f4 & 15;
            float4 w;
            if (p == 0) w = *reinterpret_cast<const float4*>(Wlf + row * 64 + c4 * 4);
            else if (p == 1) w = *reinterpret_cast<const float4*>(Wlb + row * 64 + c4 * 4);
            else {
                float4 w1 = *reinterpret_cast<const float4*>(Wrf + row * 64 + c4 * 4);
                float4 w2 = *reinterpret_cast<const float4*>(Wrb + row * 64 + c4 * 4);
                w = make_float4(w1.x + w2.x, w1.y + w2.y, w1.z + w2.z, w1.w + w2.w);
            }
            *reinterpret_cast<float4*>(&sW[row][c4 * 4]) = w;
        }
        // input tile
#pragma unroll
        for (int i = 0; i < 4; i++) {
            int f4 = t + 256 * i;
            int row = f4 >> 4, c4 = f4 & 15;
            int node = base + row;
            float4 v = make_float4(0.f, 0.f, 0.f, 0.f);
            if (node < n) {
                if (p == 2 && Xf) {
                    v = *reinterpret_cast<const float4*>(Xf + (size_t)node * 64 + c4 * 4);
                } else {
                    const ushort* src = (p == 0) ? aggf : (p == 1) ? aggb : Xb16;
                    ushort4 u = *reinterpret_cast<const ushort4*>(src + (size_t)node * 64 + c4 * 4);
                    v = make_float4(bf2f(u.x), bf2f(u.y), bf2f(u.z), bf2f(u.w));
                }
            }
            *reinterpret_cast<float4*>(&sIn[row][c4 * 4]) = v;
        }
        __syncthreads();
        for (int kc = 0; kc < 16; kc++) {
            float4 av[4], wv[4];
#pragma unroll
            for (int i = 0; i < 4; i++)
                av[i] = *reinterpret_cast<const float4*>(&sIn[ng + 16 * i][kc * 4]);
#pragma unroll
            for (int i = 0; i < 4; i++)
                wv[i] = *reinterpret_cast<const float4*>(&sW[jg + 16 * i][kc * 4]);
#pragma unroll
            for (int a = 0; a < 4; a++)
#pragma unroll
                for (int b = 0; b < 4; b++)
                    acc[a][b] += av[a].x * wv[b].x + av[a].y * wv[b].y +
                                 av[a].z * wv[b].z + av[a].w * wv[b].w;
        }
        __syncthreads();
    }
    // epilogue: bias+relu into LDS, then vectorized bf16 store
#pragma unroll
    for (int b = 0; b < 4; b++) {
        int j = jg + 16 * b;
        float bias = 0.5f * (blf[j] + blb[j]);
#pragma unroll
        for (int a = 0; a < 4; a++) {
            float v = 0.5f * acc[a][b] + bias;
            sIn[ng + 16 * a][j] = v > 0.f ? v : 0.f;
        }
    }
    __syncthreads();
#pragma unroll
    for (int i = 0; i < 4; i++) {
        int f4 = t + 256 * i;
        int row = f4 >> 4, c4 = f4 & 15;
        int node = base + row;
        if (node < n) {
            float4 v = *reinterpret_cast<const float4*>(&sIn[row][c4 * 4]);
            ushort4 o;
            o.x = f2bf(v.x); o.y = f2bf(v.y); o.z = f2bf(v.z); o.w = f2bf(v.w);
            *reinterpret_cast<ushort4*>(Out + (size_t)node * 64 + c4 * 4) = o;
        }
    }
}

// ---------------- pooling: per-block LDS [G][64] accumulator ----------------
__global__ __launch_bounds__(256) void pool_partial(const ushort* __restrict__ H,
                                                    const int* __restrict__ batch,
                                                    float* __restrict__ psum,
                                                    float* __restrict__ pcnt, int n) {
    __shared__ float ls[GG * 64];
    __shared__ float lc[GG];
    int t = threadIdx.x;
    for (int i = t; i < GG * 64; i += 256) ls[i] = 0.f;
    for (int i = t; i < GG; i += 256) lc[i] = 0.f;
    __syncthreads();
    int chunk = (n + gridDim.x - 1) / gridDim.x;
    int base = blockIdx.x * chunk;
    int end = base + chunk; if (end > n) end = n;
    int f = t & 63, r = t >> 6;
    for (int node = base + r; node < end; node += 4) {
        int g = batch[node];
        float v = bf2f(H[(size_t)node * 64 + f]);
        atomicAdd(&ls[g * 64 + f], v);
        if (f == 0) atomicAdd(&lc[g], 1.f);
    }
    __syncthreads();
    for (int i = t; i < GG * 64; i += 256) {
        float v = ls[i];
        if (v != 0.f) atomicAdd(&psum[i], v);
    }
    for (int i = t; i < GG; i += 256) {
        float v = lc[i];
        if (v != 0.f) atomicAdd(&pcnt[i], v);
    }
}

// ---------------- head ----------------
__global__ __launch_bounds__(256) void pool_final(const float* __restrict__ psum,
                                                  const float* __restrict__ pcnt,
                                                  const float* __restrict__ PW,
                                                  const float* __restrict__ Pb,
                                                  float* __restrict__ out) {
    int t = blockIdx.x * 256 + threadIdx.x;
    int g = t >> 4, o = t & 15;
    if (g >= GG) return;
    float inv = 1.f / fmaxf(pcnt[g], 1.f);
    float acc = 0.f;
#pragma unroll 8
    for (int k = 0; k < 64; k++) acc += psum[g * 64 + k] * PW[o * 64 + k];
    out[t] = acc * inv + Pb[o];
}

extern "C" void kernel_launch(void* const* d_in, const int* in_sizes, int n_in,
                              void* d_out, int out_size, void* d_ws, size_t ws_size,
                              hipStream_t stream) {
    const float* x      = (const float*)d_in[0];
    const int*   ei     = (const int*)d_in[1];
    const int*   batch  = (const int*)d_in[2];
    const float* l0f_Wl = (const float*)d_in[4];
    const float* l0f_bl = (const float*)d_in[5];
    const float* l0f_Wr = (const float*)d_in[6];
    const float* l0b_Wl = (const float*)d_in[7];
    const float* l0b_bl = (const float*)d_in[8];
    const float* l0b_Wr = (const float*)d_in[9];
    const float* l1f_Wl = (const float*)d_in[10];
    const float* l1f_bl = (const float*)d_in[11];
    const float* l1f_Wr = (const float*)d_in[12];
    const float* l1b_Wl = (const float*)d_in[13];
    const float* l1b_bl = (const float*)d_in[14];
    const float* l1b_Wr = (const float*)d_in[15];
    const float* pred_W = (const float*)d_in[16];
    const float* pred_b = (const float*)d_in[17];

    const int n = in_sizes[0] / 64;
    const int e = in_sizes[1] / 2;
    const int nb = (n + 255) / 256;

    // ---- workspace layout (int elements) ----
    int* ws = (int*)d_ws;
    size_t o = 0;
    int*   degfR = ws + o;  o += 4 * (size_t)n;          // zeroed
    int*   degbR = ws + o;  o += 4 * (size_t)n;          // zeroed
    float* psum  = (float*)(ws + o); o += GG * 64;       // zeroed
    float* pcnt  = (float*)(ws + o); o += GG;            // zeroed
    size_t zcount = o;
    int*   degf  = ws + o;  o += n;
    int*   degb  = ws + o;  o += n;
    int*   off_f = ws + o;  o += n + 1;
    int*   off_b = ws + o;  o += n + 1;
    o = (o + 3) & ~(size_t)3;
    int4*  baseF = (int4*)(ws + o); o += 4 * (size_t)n;
    int4*  baseB = (int4*)(ws + o); o += 4 * (size_t)n;
    int*   rankf = ws + o;  o += e;
    int*   rankb = ws + o;  o += e;
    int*   csr_f = ws + o;  o += e;
    int*   csr_b = ws + o;  o += e;
    int*   part_f = ws + o; o += 512;
    int*   part_b = ws + o; o += 512;
    float* invf  = (float*)(ws + o); o += n;
    float* invb  = (float*)(ws + o); o += n;
    o = (o + 3) & ~(size_t)3;
    ushort* xb    = (ushort*)(ws + o); o += (size_t)n * 32;  // [n][64] bf16 (x->h0->h1)
    ushort* aggfb = (ushort*)(ws + o); o += (size_t)n * 32;  // [n][64] bf16
    ushort* aggbb = (ushort*)(ws + o); o += (size_t)n * 32;  // [n][64] bf16

    hipMemsetAsync(ws, 0, zcount * sizeof(int), stream);

    // CSR build (once; reused by both layers)
    deg_rank<<<(e + 255) / 256, 256, 0, stream>>>(ei, degfR, degbR, rankf, rankb, e, n);
    to_bf16<<<((size_t)n * 16 + 255) / 256, 256, 0, stream>>>(x, xb, n * 16);
    sum_reps<<<nb, 256, 0, stream>>>(degfR, degbR, degf, degb, n);
    scan1<<<dim3(nb, 2), 256, 0, stream>>>(degf, degb, part_f, part_b, n);
    scan2<<<2, 512, 0, stream>>>(part_f, part_b, nb);
    scan3<<<dim3(nb, 2), 256, 0, stream>>>(degf, degb, part_f, part_b,
                                           off_f, off_b, invf, invb, n, e);
    make_base<<<nb, 256, 0, stream>>>(degfR, degbR, off_f, off_b, baseF, baseB, n);
    fill_csr<<<(e + 255) / 256, 256, 0, stream>>>(ei, baseF, baseB, rankf, rankb,
                                                  csr_f, csr_b, e);

    // layer 0: gather from x_bf16, sage pass2 from x (f32); h0_bf16 -> xb
    gather_mean_bf<<<((size_t)n * 32 + 255) / 256, 256, 0, stream>>>(
        xb, off_f, csr_f, invf, off_b, csr_b, invb, aggfb, aggbb, n);
    fused_sage<<<(n + 63) / 64, 256, 0, stream>>>(x, (const ushort*)nullptr,
        aggfb, aggbb,
        l0f_Wl, l0f_bl, l0f_Wr, l0b_Wl, l0b_bl, l0b_Wr, xb, n);

    // layer 1: gather from h0_bf16 (=xb), sage pass2 from xb; h1_bf16 -> xb
    gather_mean_bf<<<((size_t)n * 32 + 255) / 256, 256, 0, stream>>>(
        xb, off_f, csr_f, invf, off_b, csr_b, invb, aggfb, aggbb, n);
    fused_sage<<<(n + 63) / 64, 256, 0, stream>>>((const float*)nullptr, xb,
        aggfb, aggbb,
        l1f_Wl, l1f_bl, l1f_Wr, l1b_Wl, l1b_bl, l1b_Wr, xb, n);

    // pooling + head
    pool_partial<<<256, 256, 0, stream>>>(xb, batch, psum, pcnt, n);
    pool_final<<<8, 256, 0, stream>>>(psum, pcnt, pred_W, pred_b, (float*)d_out);
}

// Round 6
// 424.563 us; speedup vs baseline: 2.4830x; 2.4830x over previous
//
#include <hip/hip_runtime.h>
#include <hip/hip_bf16.h>

#define GG 128   // num_graphs (static in problem)

// ---------------- bf16 helpers (RNE) ----------------
__device__ __forceinline__ ushort f2bf(float f) {
    union { float f; unsigned u; } v; v.f = f;
    unsigned r = v.u + 0x7FFF + ((v.u >> 16) & 1);
    return (ushort)(r >> 16);
}
__device__ __forceinline__ float bf2f(ushort s) {
    union { unsigned u; float f; } v; v.u = ((unsigned)s) << 16;
    return v.f;
}

// ---------------- f32 -> bf16 convert (vectorized) ----------------
__global__ __launch_bounds__(256) void to_bf16(const float* __restrict__ X,
                                               ushort* __restrict__ Xb, int n4) {
    int i = blockIdx.x * 256 + threadIdx.x;
    if (i >= n4) return;
    float4 v = reinterpret_cast<const float4*>(X)[i];
    ushort4 o;
    o.x = f2bf(v.x); o.y = f2bf(v.y); o.z = f2bf(v.z); o.w = f2bf(v.w);
    reinterpret_cast<ushort4*>(Xb)[i] = o;
}

// ------------- degrees + ranks, 4-replica split (returning atomics) --------
__global__ __launch_bounds__(256) void deg_rank(const int* __restrict__ ei,
                                                int* __restrict__ degfR,
                                                int* __restrict__ degbR,
                                                int* __restrict__ rankf,
                                                int* __restrict__ rankb,
                                                int e, int n) {
    int i = blockIdx.x * 256 + threadIdx.x;
    if (i >= e) return;
    int s = ei[i], d = ei[e + i];
    int r = i & 3;
    rankf[i] = atomicAdd(degfR + (size_t)r * n + d, 1);
    rankb[i] = atomicAdd(degbR + (size_t)r * n + s, 1);
}

// ------------- sum replicas -> full degrees ---------------------------------
__global__ __launch_bounds__(256) void sum_reps(const int* __restrict__ degfR,
                                                const int* __restrict__ degbR,
                                                int* __restrict__ degf,
                                                int* __restrict__ degb, int n) {
    int i = blockIdx.x * 256 + threadIdx.x;
    if (i >= n) return;
    degf[i] = degfR[i] + degfR[n + i] + degfR[2 * (size_t)n + i] + degfR[3 * (size_t)n + i];
    degb[i] = degbR[i] + degbR[n + i] + degbR[2 * (size_t)n + i] + degbR[3 * (size_t)n + i];
}

// ---------------- 3-phase exclusive scan (f and b via blockIdx.y) -----------
__global__ __launch_bounds__(256) void scan1(const int* __restrict__ degf,
                                             const int* __restrict__ degb,
                                             int* __restrict__ part_f,
                                             int* __restrict__ part_b, int n) {
    const int* deg = blockIdx.y ? degb : degf;
    int* partial = blockIdx.y ? part_b : part_f;
    __shared__ int s[256];
    int t = threadIdx.x, i = blockIdx.x * 256 + t;
    s[t] = (i < n) ? deg[i] : 0;
    __syncthreads();
    for (int o = 128; o > 0; o >>= 1) {
        if (t < o) s[t] += s[t + o];
        __syncthreads();
    }
    if (t == 0) partial[blockIdx.x] = s[0];
}

__global__ __launch_bounds__(512) void scan2(int* __restrict__ part_f,
                                             int* __restrict__ part_b, int nb) {
    int* partial = blockIdx.x ? part_b : part_f;
    __shared__ int s[512];
    int t = threadIdx.x;
    int v = (t < nb) ? partial[t] : 0;
    s[t] = v;
    __syncthreads();
    for (int o = 1; o < 512; o <<= 1) {
        int u = (t >= o) ? s[t - o] : 0;
        __syncthreads();
        s[t] += u;
        __syncthreads();
    }
    if (t < nb) partial[t] = s[t] - v;  // exclusive
}

__global__ __launch_bounds__(256) void scan3(const int* __restrict__ degf,
                                             const int* __restrict__ degb,
                                             const int* __restrict__ part_f,
                                             const int* __restrict__ part_b,
                                             int* __restrict__ off_f,
                                             int* __restrict__ off_b,
                                             float* __restrict__ invf,
                                             float* __restrict__ invb,
                                             int n, int e) {
    const int* deg = blockIdx.y ? degb : degf;
    const int* partial = blockIdx.y ? part_b : part_f;
    int* off = blockIdx.y ? off_b : off_f;
    float* inv = blockIdx.y ? invb : invf;
    __shared__ int s[256];
    int t = threadIdx.x, i = blockIdx.x * 256 + t;
    int v = (i < n) ? deg[i] : 0;
    s[t] = v;
    __syncthreads();
    for (int o = 1; o < 256; o <<= 1) {
        int u = (t >= o) ? s[t - o] : 0;
        __syncthreads();
        s[t] += u;
        __syncthreads();
    }
    if (i < n) {
        off[i] = partial[blockIdx.x] + s[t] - v;
        inv[i] = 1.f / fmaxf((float)v, 1.f);
    }
    if (i == n - 1) off[n] = e;
}

// ------------- per-node int4 base = off + replica prefix --------------------
__global__ __launch_bounds__(256) void make_base(const int* __restrict__ degfR,
                                                 const int* __restrict__ degbR,
                                                 const int* __restrict__ off_f,
                                                 const int* __restrict__ off_b,
                                                 int4* __restrict__ baseF,
                                                 int4* __restrict__ baseB, int n) {
    int i = blockIdx.x * 256 + threadIdx.x;
    if (i >= n) return;
    {
        int o = off_f[i];
        int c0 = degfR[i], c1 = degfR[n + i], c2 = degfR[2 * (size_t)n + i];
        baseF[i] = make_int4(o, o + c0, o + c0 + c1, o + c0 + c1 + c2);
    }
    {
        int o = off_b[i];
        int c0 = degbR[i], c1 = degbR[n + i], c2 = degbR[2 * (size_t)n + i];
        baseB[i] = make_int4(o, o + c0, o + c0 + c1, o + c0 + c1 + c2);
    }
}

// ---------------- CSR fill: atomic-free scattered stores --------------------
__global__ __launch_bounds__(256) void fill_csr(const int* __restrict__ ei,
                                                const int4* __restrict__ baseF,
                                                const int4* __restrict__ baseB,
                                                const int* __restrict__ rankf,
                                                const int* __restrict__ rankb,
                                                int* __restrict__ csr_f,
                                                int* __restrict__ csr_b, int e) {
    int i = blockIdx.x * 256 + threadIdx.x;
    if (i >= e) return;
    int s = ei[i], d = ei[e + i];
    int r = i & 3;
    int4 bf = baseF[d];
    int4 bb = baseB[s];
    int basef = (r < 2) ? (r == 0 ? bf.x : bf.y) : (r == 2 ? bf.z : bf.w);
    int baseb = (r < 2) ? (r == 0 ? bb.x : bb.y) : (r == 2 ? bb.z : bb.w);
    csr_f[basef + rankf[i]] = s;
    csr_b[baseb + rankb[i]] = d;
}

// ---- gather-mean: bf16 reads, f32 accumulate, f32 agg writes ---------------
// 32 threads/node (16 per direction), ushort4 = 8B/lane, 128B/row coalesced.
__global__ __launch_bounds__(256) void gather_mean_bf(
    const ushort* __restrict__ Xb,
    const int* __restrict__ off_f, const int* __restrict__ csr_f,
    const float* __restrict__ invf,
    const int* __restrict__ off_b, const int* __restrict__ csr_b,
    const float* __restrict__ invb,
    float* __restrict__ aggf, float* __restrict__ aggb, int n) {
    int tid = blockIdx.x * 256 + threadIdx.x;
    int node = tid >> 5;
    if (node >= n) return;
    int dir = (tid >> 4) & 1;
    int c = (tid & 15) * 4;
    const int* off = dir ? off_b : off_f;
    const int* csr = dir ? csr_b : csr_f;
    const float* inv = dir ? invb : invf;
    float* agg = dir ? aggb : aggf;

    int b = off[node], en = off[node + 1];
    float ax = 0.f, ay = 0.f, az = 0.f, aw = 0.f;
    int k = b;
    for (; k + 3 < en; k += 4) {
        int n0 = csr[k], n1 = csr[k + 1], n2 = csr[k + 2], n3 = csr[k + 3];
        ushort4 v0 = *reinterpret_cast<const ushort4*>(Xb + (size_t)n0 * 64 + c);
        ushort4 v1 = *reinterpret_cast<const ushort4*>(Xb + (size_t)n1 * 64 + c);
        ushort4 v2 = *reinterpret_cast<const ushort4*>(Xb + (size_t)n2 * 64 + c);
        ushort4 v3 = *reinterpret_cast<const ushort4*>(Xb + (size_t)n3 * 64 + c);
        ax += bf2f(v0.x) + bf2f(v1.x) + bf2f(v2.x) + bf2f(v3.x);
        ay += bf2f(v0.y) + bf2f(v1.y) + bf2f(v2.y) + bf2f(v3.y);
        az += bf2f(v0.z) + bf2f(v1.z) + bf2f(v2.z) + bf2f(v3.z);
        aw += bf2f(v0.w) + bf2f(v1.w) + bf2f(v2.w) + bf2f(v3.w);
    }
    for (; k < en; k++) {
        int s = csr[k];
        ushort4 v = *reinterpret_cast<const ushort4*>(Xb + (size_t)s * 64 + c);
        ax += bf2f(v.x); ay += bf2f(v.y); az += bf2f(v.z); aw += bf2f(v.w);
    }
    float iv = inv[node];
    float4 r = make_float4(ax * iv, ay * iv, az * iv, aw * iv);
    *reinterpret_cast<float4*>(agg + (size_t)node * 64 + c) = r;
}

// ---------------- fused bidirectional SAGE layer (R3 shape, f32) ------------
// out = relu(0.5*(mean_f@Wlf^T + mean_b@Wlb^T + x@(Wrf+Wrb)^T + blf+blb))
// Optional secondary bf16 output (OutB) for the next layer's gather.
__global__ __launch_bounds__(256) void fused_sage(
    const float* __restrict__ X,
    const float* __restrict__ aggf, const float* __restrict__ aggb,
    const float* __restrict__ Wlf, const float* __restrict__ blf,
    const float* __restrict__ Wrf,
    const float* __restrict__ Wlb, const float* __restrict__ blb,
    const float* __restrict__ Wrb,
    float* __restrict__ Out, ushort* __restrict__ OutB, int n)
{
    __shared__ float sIn[64][68];
    __shared__ float sW[64][68];
    const int t = threadIdx.x;
    const int base = blockIdx.x * 64;
    const int jg = t & 15;
    const int ng = t >> 4;

    float acc[4][4];
#pragma unroll
    for (int a = 0; a < 4; a++)
#pragma unroll
        for (int b = 0; b < 4; b++) acc[a][b] = 0.f;

    for (int p = 0; p < 3; p++) {
        const float* src = (p == 0) ? aggf : (p == 1) ? aggb : X;
#pragma unroll
        for (int i = 0; i < 4; i++) {
            int f4 = t + 256 * i;
            int row = f4 >> 4, c4 = f4 & 15;
            int grow = base + row;
            float4 v = make_float4(0.f, 0.f, 0.f, 0.f);
            if (grow < n)
                v = *reinterpret_cast<const float4*>(src + (size_t)grow * 64 + c4 * 4);
            *reinterpret_cast<float4*>(&sIn[row][c4 * 4]) = v;
        }
#pragma unroll
        for (int i = 0; i < 4; i++) {
            int f4 = t + 256 * i;
            int row = f4 >> 4, c4 = f4 & 15;
            float4 w;
            if (p == 0) w = *reinterpret_cast<const float4*>(Wlf + row * 64 + c4 * 4);
            else if (p == 1) w = *reinterpret_cast<const float4*>(Wlb + row * 64 + c4 * 4);
            else {
                float4 w1 = *reinterpret_cast<const float4*>(Wrf + row * 64 + c4 * 4);
                float4 w2 = *reinterpret_cast<const float4*>(Wrb + row * 64 + c4 * 4);
                w = make_float4(w1.x + w2.x, w1.y + w2.y, w1.z + w2.z, w1.w + w2.w);
            }
            *reinterpret_cast<float4*>(&sW[row][c4 * 4]) = w;
        }
        __syncthreads();
        for (int kc = 0; kc < 16; kc++) {
            float4 av[4], wv[4];
#pragma unroll
            for (int i = 0; i < 4; i++)
                av[i] = *reinterpret_cast<const float4*>(&sIn[ng + 16 * i][kc * 4]);
#pragma unroll
            for (int i = 0; i < 4; i++)
                wv[i] = *reinterpret_cast<const float4*>(&sW[jg + 16 * i][kc * 4]);
#pragma unroll
            for (int a = 0; a < 4; a++)
#pragma unroll
                for (int b = 0; b < 4; b++)
                    acc[a][b] += av[a].x * wv[b].x + av[a].y * wv[b].y +
                                 av[a].z * wv[b].z + av[a].w * wv[b].w;
        }
        __syncthreads();
    }
#pragma unroll
    for (int b = 0; b < 4; b++) {
        int j = jg + 16 * b;
        float bias = 0.5f * (blf[j] + blb[j]);
#pragma unroll
        for (int a = 0; a < 4; a++) {
            int grow = base + ng + 16 * a;
            if (grow < n) {
                float v = 0.5f * acc[a][b] + bias;
                v = v > 0.f ? v : 0.f;
                Out[(size_t)grow * 64 + j] = v;
                if (OutB) OutB[(size_t)grow * 64 + j] = f2bf(v);
            }
        }
    }
}

// ---- pooling: sorted batch -> register accumulate, flush on graph change ---
__global__ __launch_bounds__(256) void pool_partial(const float* __restrict__ H,
                                                    const int* __restrict__ batch,
                                                    float* __restrict__ psum,
                                                    float* __restrict__ pcnt, int n) {
    __shared__ float ls[GG * 64];
    __shared__ float lc[GG];
    int t = threadIdx.x;
    for (int i = t; i < GG * 64; i += 256) ls[i] = 0.f;
    for (int i = t; i < GG; i += 256) lc[i] = 0.f;
    __syncthreads();
    int chunk = (n + gridDim.x - 1) / gridDim.x;
    int base = blockIdx.x * chunk;
    int end = base + chunk; if (end > n) end = n;
    int f = t & 63, r = t >> 6;
    float acc = 0.f; int cnt = 0; int curg = -1;
    for (int node = base + r; node < end; node += 4) {
        int g = batch[node];
        if (g != curg) {
            if (curg >= 0) {
                atomicAdd(&ls[curg * 64 + f], acc);
                if (f == 0) atomicAdd(&lc[curg], (float)cnt);
            }
            curg = g; acc = 0.f; cnt = 0;
        }
        acc += H[(size_t)node * 64 + f];
        cnt++;
    }
    if (curg >= 0) {
        atomicAdd(&ls[curg * 64 + f], acc);
        if (f == 0) atomicAdd(&lc[curg], (float)cnt);
    }
    __syncthreads();
    for (int i = t; i < GG * 64; i += 256) {
        float v = ls[i];
        if (v != 0.f) atomicAdd(&psum[i], v);
    }
    for (int i = t; i < GG; i += 256) {
        float v = lc[i];
        if (v != 0.f) atomicAdd(&pcnt[i], v);
    }
}

// ---------------- head ----------------
__global__ __launch_bounds__(256) void pool_final(const float* __restrict__ psum,
                                                  const float* __restrict__ pcnt,
                                                  const float* __restrict__ PW,
                                                  const float* __restrict__ Pb,
                                                  float* __restrict__ out) {
    int t = blockIdx.x * 256 + threadIdx.x;
    int g = t >> 4, o = t & 15;
    if (g >= GG) return;
    float inv = 1.f / fmaxf(pcnt[g], 1.f);
    float acc = 0.f;
#pragma unroll 8
    for (int k = 0; k < 64; k++) acc += psum[g * 64 + k] * PW[o * 64 + k];
    out[t] = acc * inv + Pb[o];
}

extern "C" void kernel_launch(void* const* d_in, const int* in_sizes, int n_in,
                              void* d_out, int out_size, void* d_ws, size_t ws_size,
                              hipStream_t stream) {
    const float* x      = (const float*)d_in[0];
    const int*   ei     = (const int*)d_in[1];
    const int*   batch  = (const int*)d_in[2];
    const float* l0f_Wl = (const float*)d_in[4];
    const float* l0f_bl = (const float*)d_in[5];
    const float* l0f_Wr = (const float*)d_in[6];
    const float* l0b_Wl = (const float*)d_in[7];
    const float* l0b_bl = (const float*)d_in[8];
    const float* l0b_Wr = (const float*)d_in[9];
    const float* l1f_Wl = (const float*)d_in[10];
    const float* l1f_bl = (const float*)d_in[11];
    const float* l1f_Wr = (const float*)d_in[12];
    const float* l1b_Wl = (const float*)d_in[13];
    const float* l1b_bl = (const float*)d_in[14];
    const float* l1b_Wr = (const float*)d_in[15];
    const float* pred_W = (const float*)d_in[16];
    const float* pred_b = (const float*)d_in[17];

    const int n = in_sizes[0] / 64;
    const int e = in_sizes[1] / 2;
    const size_t N64 = (size_t)n * 64;
    const int nb = (n + 255) / 256;

    // ---- workspace layout (int elements) ----
    int* ws = (int*)d_ws;
    size_t o = 0;
    int*   degfR = ws + o;  o += 4 * (size_t)n;          // zeroed
    int*   degbR = ws + o;  o += 4 * (size_t)n;          // zeroed
    float* psum  = (float*)(ws + o); o += GG * 64;       // zeroed
    float* pcnt  = (float*)(ws + o); o += GG;            // zeroed
    size_t zcount = o;
    int*   degf  = ws + o;  o += n;
    int*   degb  = ws + o;  o += n;
    int*   off_f = ws + o;  o += n + 1;
    int*   off_b = ws + o;  o += n + 1;
    o = (o + 3) & ~(size_t)3;
    int4*  baseF = (int4*)(ws + o); o += 4 * (size_t)n;
    int4*  baseB = (int4*)(ws + o); o += 4 * (size_t)n;
    int*   rankf = ws + o;  o += e;
    int*   rankb = ws + o;  o += e;
    int*   csr_f = ws + o;  o += e;
    int*   csr_b = ws + o;  o += e;
    int*   part_f = ws + o; o += 512;
    int*   part_b = ws + o; o += 512;
    float* invf  = (float*)(ws + o); o += n;
    float* invb  = (float*)(ws + o); o += n;
    o = (o + 3) & ~(size_t)3;
    float* aggf  = (float*)(ws + o); o += N64;           // [n][64] f32
    float* aggb  = (float*)(ws + o); o += N64;           // [n][64] f32
    float* h0    = (float*)(ws + o); o += N64;           // [n][64] f32
    ushort* xb   = (ushort*)(ws + o); o += (size_t)n * 32; // [n][64] bf16 (x, then h0)
    float* h1    = aggf;   // alias (safe: per-block read-before-write)

    hipMemsetAsync(ws, 0, zcount * sizeof(int), stream);

    // CSR build (once; reused by both layers)
    deg_rank<<<(e + 255) / 256, 256, 0, stream>>>(ei, degfR, degbR, rankf, rankb, e, n);
    to_bf16<<<((size_t)n * 16 + 255) / 256, 256, 0, stream>>>(x, xb, n * 16);
    sum_reps<<<nb, 256, 0, stream>>>(degfR, degbR, degf, degb, n);
    scan1<<<dim3(nb, 2), 256, 0, stream>>>(degf, degb, part_f, part_b, n);
    scan2<<<2, 512, 0, stream>>>(part_f, part_b, nb);
    scan3<<<dim3(nb, 2), 256, 0, stream>>>(degf, degb, part_f, part_b,
                                           off_f, off_b, invf, invb, n, e);
    make_base<<<nb, 256, 0, stream>>>(degfR, degbR, off_f, off_b, baseF, baseB, n);
    fill_csr<<<(e + 255) / 256, 256, 0, stream>>>(ei, baseF, baseB, rankf, rankb,
                                                  csr_f, csr_b, e);

    // layer 0: gather bf16(x), sage f32 -> h0 (+h0 bf16 into xb)
    gather_mean_bf<<<((size_t)n * 32 + 255) / 256, 256, 0, stream>>>(
        xb, off_f, csr_f, invf, off_b, csr_b, invb, aggf, aggb, n);
    fused_sage<<<(n + 63) / 64, 256, 0, stream>>>(x, aggf, aggb,
        l0f_Wl, l0f_bl, l0f_Wr, l0b_Wl, l0b_bl, l0b_Wr, h0, xb, n);

    // layer 1: gather bf16(h0), sage f32 -> h1 (no bf16 output)
    gather_mean_bf<<<((size_t)n * 32 + 255) / 256, 256, 0, stream>>>(
        xb, off_f, csr_f, invf, off_b, csr_b, invb, aggf, aggb, n);
    fused_sage<<<(n + 63) / 64, 256, 0, stream>>>(h0, aggf, aggb,
        l1f_Wl, l1f_bl, l1f_Wr, l1b_Wl, l1b_bl, l1b_Wr, h1, (ushort*)nullptr, n);

    // pooling + head
    pool_partial<<<256, 256, 0, stream>>>(h1, batch, psum, pcnt, n);
    pool_final<<<8, 256, 0, stream>>>(psum, pcnt, pred_W, pred_b, (float*)d_out);
}

// Round 7
// 423.075 us; speedup vs baseline: 2.4918x; 1.0035x over previous
//
#include <hip/hip_runtime.h>
#include <hip/hip_bf16.h>

#define GG 128   // num_graphs (static in problem)

// ---------------- bf16 helpers (RNE) ----------------
__device__ __forceinline__ ushort f2bf(float f) {
    union { float f; unsigned u; } v; v.f = f;
    unsigned r = v.u + 0x7FFF + ((v.u >> 16) & 1);
    return (ushort)(r >> 16);
}
__device__ __forceinline__ float bf2f(ushort s) {
    union { unsigned u; float f; } v; v.u = ((unsigned)s) << 16;
    return v.f;
}

// ---------------- f32 -> bf16 convert (vectorized) ----------------
__global__ __launch_bounds__(256) void to_bf16(const float* __restrict__ X,
                                               ushort* __restrict__ Xb, int n4) {
    int i = blockIdx.x * 256 + threadIdx.x;
    if (i >= n4) return;
    float4 v = reinterpret_cast<const float4*>(X)[i];
    ushort4 o;
    o.x = f2bf(v.x); o.y = f2bf(v.y); o.z = f2bf(v.z); o.w = f2bf(v.w);
    reinterpret_cast<ushort4*>(Xb)[i] = o;
}

// ------- degrees + ranks, 4 edges/thread, 8 returning atomics in flight -----
// replica index == int4 component -> a thread's atomics hit 4 replica arrays
__global__ __launch_bounds__(256) void deg_rank4(const int* __restrict__ ei,
                                                 int* __restrict__ degfR,
                                                 int* __restrict__ degbR,
                                                 int* __restrict__ rankf,
                                                 int* __restrict__ rankb,
                                                 int e4, int e, int n) {
    int i = blockIdx.x * 256 + threadIdx.x;
    if (i >= e4) return;
    int4 s4 = reinterpret_cast<const int4*>(ei)[i];
    int4 d4 = reinterpret_cast<const int4*>(ei + e)[i];
    int4 rf, rb;
    rf.x = atomicAdd(degfR + d4.x, 1);
    rf.y = atomicAdd(degfR + (size_t)n + d4.y, 1);
    rf.z = atomicAdd(degfR + 2 * (size_t)n + d4.z, 1);
    rf.w = atomicAdd(degfR + 3 * (size_t)n + d4.w, 1);
    rb.x = atomicAdd(degbR + s4.x, 1);
    rb.y = atomicAdd(degbR + (size_t)n + s4.y, 1);
    rb.z = atomicAdd(degbR + 2 * (size_t)n + s4.z, 1);
    rb.w = atomicAdd(degbR + 3 * (size_t)n + s4.w, 1);
    reinterpret_cast<int4*>(rankf)[i] = rf;
    reinterpret_cast<int4*>(rankb)[i] = rb;
}

// scalar fallback (e not divisible by 4)
__global__ __launch_bounds__(256) void deg_rank1(const int* __restrict__ ei,
                                                 int* __restrict__ degfR,
                                                 int* __restrict__ degbR,
                                                 int* __restrict__ rankf,
                                                 int* __restrict__ rankb,
                                                 int e, int n) {
    int i = blockIdx.x * 256 + threadIdx.x;
    if (i >= e) return;
    int s = ei[i], d = ei[e + i];
    int r = i & 3;
    rankf[i] = atomicAdd(degfR + (size_t)r * n + d, 1);
    rankb[i] = atomicAdd(degbR + (size_t)r * n + s, 1);
}

// ------------- sum replicas -> full degrees ---------------------------------
__global__ __launch_bounds__(256) void sum_reps(const int* __restrict__ degfR,
                                                const int* __restrict__ degbR,
                                                int* __restrict__ degf,
                                                int* __restrict__ degb, int n) {
    int i = blockIdx.x * 256 + threadIdx.x;
    if (i >= n) return;
    degf[i] = degfR[i] + degfR[n + i] + degfR[2 * (size_t)n + i] + degfR[3 * (size_t)n + i];
    degb[i] = degbR[i] + degbR[n + i] + degbR[2 * (size_t)n + i] + degbR[3 * (size_t)n + i];
}

// ---------------- 3-phase exclusive scan (f and b via blockIdx.y) -----------
__global__ __launch_bounds__(256) void scan1(const int* __restrict__ degf,
                                             const int* __restrict__ degb,
                                             int* __restrict__ part_f,
                                             int* __restrict__ part_b, int n) {
    const int* deg = blockIdx.y ? degb : degf;
    int* partial = blockIdx.y ? part_b : part_f;
    __shared__ int s[256];
    int t = threadIdx.x, i = blockIdx.x * 256 + t;
    s[t] = (i < n) ? deg[i] : 0;
    __syncthreads();
    for (int o = 128; o > 0; o >>= 1) {
        if (t < o) s[t] += s[t + o];
        __syncthreads();
    }
    if (t == 0) partial[blockIdx.x] = s[0];
}

__global__ __launch_bounds__(512) void scan2(int* __restrict__ part_f,
                                             int* __restrict__ part_b, int nb) {
    int* partial = blockIdx.x ? part_b : part_f;
    __shared__ int s[512];
    int t = threadIdx.x;
    int v = (t < nb) ? partial[t] : 0;
    s[t] = v;
    __syncthreads();
    for (int o = 1; o < 512; o <<= 1) {
        int u = (t >= o) ? s[t - o] : 0;
        __syncthreads();
        s[t] += u;
        __syncthreads();
    }
    if (t < nb) partial[t] = s[t] - v;  // exclusive
}

__global__ __launch_bounds__(256) void scan3(const int* __restrict__ degf,
                                             const int* __restrict__ degb,
                                             const int* __restrict__ part_f,
                                             const int* __restrict__ part_b,
                                             int* __restrict__ off_f,
                                             int* __restrict__ off_b,
                                             float* __restrict__ invf,
                                             float* __restrict__ invb,
                                             int n, int e) {
    const int* deg = blockIdx.y ? degb : degf;
    const int* partial = blockIdx.y ? part_b : part_f;
    int* off = blockIdx.y ? off_b : off_f;
    float* inv = blockIdx.y ? invb : invf;
    __shared__ int s[256];
    int t = threadIdx.x, i = blockIdx.x * 256 + t;
    int v = (i < n) ? deg[i] : 0;
    s[t] = v;
    __syncthreads();
    for (int o = 1; o < 256; o <<= 1) {
        int u = (t >= o) ? s[t - o] : 0;
        __syncthreads();
        s[t] += u;
        __syncthreads();
    }
    if (i < n) {
        off[i] = partial[blockIdx.x] + s[t] - v;
        inv[i] = 1.f / fmaxf((float)v, 1.f);
    }
    if (i == n - 1) off[n] = e;
}

// ------------- per-node int4 base = off + replica prefix --------------------
__global__ __launch_bounds__(256) void make_base(const int* __restrict__ degfR,
                                                 const int* __restrict__ degbR,
                                                 const int* __restrict__ off_f,
                                                 const int* __restrict__ off_b,
                                                 int4* __restrict__ baseF,
                                                 int4* __restrict__ baseB, int n) {
    int i = blockIdx.x * 256 + threadIdx.x;
    if (i >= n) return;
    {
        int o = off_f[i];
        int c0 = degfR[i], c1 = degfR[n + i], c2 = degfR[2 * (size_t)n + i];
        baseF[i] = make_int4(o, o + c0, o + c0 + c1, o + c0 + c1 + c2);
    }
    {
        int o = off_b[i];
        int c0 = degbR[i], c1 = degbR[n + i], c2 = degbR[2 * (size_t)n + i];
        baseB[i] = make_int4(o, o + c0, o + c0 + c1, o + c0 + c1 + c2);
    }
}

// -------- CSR fill: 4 edges/thread, atomic-free, 8 indep. scatter stores ----
__global__ __launch_bounds__(256) void fill_csr4(const int* __restrict__ ei,
                                                 const int4* __restrict__ baseF,
                                                 const int4* __restrict__ baseB,
                                                 const int* __restrict__ rankf,
                                                 const int* __restrict__ rankb,
                                                 int* __restrict__ csr_f,
                                                 int* __restrict__ csr_b,
                                                 int e4, int e) {
    int i = blockIdx.x * 256 + threadIdx.x;
    if (i >= e4) return;
    int4 s4 = reinterpret_cast<const int4*>(ei)[i];
    int4 d4 = reinterpret_cast<const int4*>(ei + e)[i];
    int4 rf = reinterpret_cast<const int4*>(rankf)[i];
    int4 rb = reinterpret_cast<const int4*>(rankb)[i];
    csr_f[baseF[d4.x].x + rf.x] = s4.x;
    csr_f[baseF[d4.y].y + rf.y] = s4.y;
    csr_f[baseF[d4.z].z + rf.z] = s4.z;
    csr_f[baseF[d4.w].w + rf.w] = s4.w;
    csr_b[baseB[s4.x].x + rb.x] = d4.x;
    csr_b[baseB[s4.y].y + rb.y] = d4.y;
    csr_b[baseB[s4.z].z + rb.z] = d4.z;
    csr_b[baseB[s4.w].w + rb.w] = d4.w;
}

__global__ __launch_bounds__(256) void fill_csr1(const int* __restrict__ ei,
                                                 const int4* __restrict__ baseF,
                                                 const int4* __restrict__ baseB,
                                                 const int* __restrict__ rankf,
                                                 const int* __restrict__ rankb,
                                                 int* __restrict__ csr_f,
                                                 int* __restrict__ csr_b, int e) {
    int i = blockIdx.x * 256 + threadIdx.x;
    if (i >= e) return;
    int s = ei[i], d = ei[e + i];
    int r = i & 3;
    int4 bf = baseF[d];
    int4 bb = baseB[s];
    int basef = (r < 2) ? (r == 0 ? bf.x : bf.y) : (r == 2 ? bf.z : bf.w);
    int baseb = (r < 2) ? (r == 0 ? bb.x : bb.y) : (r == 2 ? bb.z : bb.w);
    csr_f[basef + rankf[i]] = s;
    csr_b[baseb + rankb[i]] = d;
}

// ---- gather-mean: bf16 reads, f32 accumulate, f32 agg writes ---------------
__global__ __launch_bounds__(256) void gather_mean_bf(
    const ushort* __restrict__ Xb,
    const int* __restrict__ off_f, const int* __restrict__ csr_f,
    const float* __restrict__ invf,
    const int* __restrict__ off_b, const int* __restrict__ csr_b,
    const float* __restrict__ invb,
    float* __restrict__ aggf, float* __restrict__ aggb, int n) {
    int tid = blockIdx.x * 256 + threadIdx.x;
    int node = tid >> 5;
    if (node >= n) return;
    int dir = (tid >> 4) & 1;
    int c = (tid & 15) * 4;
    const int* off = dir ? off_b : off_f;
    const int* csr = dir ? csr_b : csr_f;
    const float* inv = dir ? invb : invf;
    float* agg = dir ? aggb : aggf;

    int b = off[node], en = off[node + 1];
    float ax = 0.f, ay = 0.f, az = 0.f, aw = 0.f;
    int k = b;
    for (; k + 3 < en; k += 4) {
        int n0 = csr[k], n1 = csr[k + 1], n2 = csr[k + 2], n3 = csr[k + 3];
        ushort4 v0 = *reinterpret_cast<const ushort4*>(Xb + (size_t)n0 * 64 + c);
        ushort4 v1 = *reinterpret_cast<const ushort4*>(Xb + (size_t)n1 * 64 + c);
        ushort4 v2 = *reinterpret_cast<const ushort4*>(Xb + (size_t)n2 * 64 + c);
        ushort4 v3 = *reinterpret_cast<const ushort4*>(Xb + (size_t)n3 * 64 + c);
        ax += bf2f(v0.x) + bf2f(v1.x) + bf2f(v2.x) + bf2f(v3.x);
        ay += bf2f(v0.y) + bf2f(v1.y) + bf2f(v2.y) + bf2f(v3.y);
        az += bf2f(v0.z) + bf2f(v1.z) + bf2f(v2.z) + bf2f(v3.z);
        aw += bf2f(v0.w) + bf2f(v1.w) + bf2f(v2.w) + bf2f(v3.w);
    }
    for (; k < en; k++) {
        int s = csr[k];
        ushort4 v = *reinterpret_cast<const ushort4*>(Xb + (size_t)s * 64 + c);
        ax += bf2f(v.x); ay += bf2f(v.y); az += bf2f(v.z); aw += bf2f(v.w);
    }
    float iv = inv[node];
    float4 r = make_float4(ax * iv, ay * iv, az * iv, aw * iv);
    *reinterpret_cast<float4*>(agg + (size_t)node * 64 + c) = r;
}

// ---------------- fused bidirectional SAGE layer (bf16 in/out) --------------
// out_bf = relu(0.5*(mean_f@Wlf^T + mean_b@Wlb^T + xb@(Wrf+Wrb)^T + blf+blb))
__global__ __launch_bounds__(256) void fused_sage(
    const ushort* __restrict__ Xb,
    const float* __restrict__ aggf, const float* __restrict__ aggb,
    const float* __restrict__ Wlf, const float* __restrict__ blf,
    const float* __restrict__ Wrf,
    const float* __restrict__ Wlb, const float* __restrict__ blb,
    const float* __restrict__ Wrb,
    ushort* __restrict__ OutB, int n)
{
    __shared__ float sIn[64][68];
    __shared__ float sW[64][68];
    const int t = threadIdx.x;
    const int base = blockIdx.x * 64;
    const int jg = t & 15;
    const int ng = t >> 4;

    float acc[4][4];
#pragma unroll
    for (int a = 0; a < 4; a++)
#pragma unroll
        for (int b = 0; b < 4; b++) acc[a][b] = 0.f;

    for (int p = 0; p < 3; p++) {
        // input tile
#pragma unroll
        for (int i = 0; i < 4; i++) {
            int f4 = t + 256 * i;
            int row = f4 >> 4, c4 = f4 & 15;
            int grow = base + row;
            float4 v = make_float4(0.f, 0.f, 0.f, 0.f);
            if (grow < n) {
                if (p < 2) {
                    const float* src = p ? aggb : aggf;
                    v = *reinterpret_cast<const float4*>(src + (size_t)grow * 64 + c4 * 4);
                } else {
                    ushort4 u = *reinterpret_cast<const ushort4*>(Xb + (size_t)grow * 64 + c4 * 4);
                    v = make_float4(bf2f(u.x), bf2f(u.y), bf2f(u.z), bf2f(u.w));
                }
            }
            *reinterpret_cast<float4*>(&sIn[row][c4 * 4]) = v;
        }
        // weights
#pragma unroll
        for (int i = 0; i < 4; i++) {
            int f4 = t + 256 * i;
            int row = f4 >> 4, c4 = f4 & 15;
            float4 w;
            if (p == 0) w = *reinterpret_cast<const float4*>(Wlf + row * 64 + c4 * 4);
            else if (p == 1) w = *reinterpret_cast<const float4*>(Wlb + row * 64 + c4 * 4);
            else {
                float4 w1 = *reinterpret_cast<const float4*>(Wrf + row * 64 + c4 * 4);
                float4 w2 = *reinterpret_cast<const float4*>(Wrb + row * 64 + c4 * 4);
                w = make_float4(w1.x + w2.x, w1.y + w2.y, w1.z + w2.z, w1.w + w2.w);
            }
            *reinterpret_cast<float4*>(&sW[row][c4 * 4]) = w;
        }
        __syncthreads();
        for (int kc = 0; kc < 16; kc++) {
            float4 av[4], wv[4];
#pragma unroll
            for (int i = 0; i < 4; i++)
                av[i] = *reinterpret_cast<const float4*>(&sIn[ng + 16 * i][kc * 4]);
#pragma unroll
            for (int i = 0; i < 4; i++)
                wv[i] = *reinterpret_cast<const float4*>(&sW[jg + 16 * i][kc * 4]);
#pragma unroll
            for (int a = 0; a < 4; a++)
#pragma unroll
                for (int b = 0; b < 4; b++)
                    acc[a][b] += av[a].x * wv[b].x + av[a].y * wv[b].y +
                                 av[a].z * wv[b].z + av[a].w * wv[b].w;
        }
        __syncthreads();
    }
#pragma unroll
    for (int b = 0; b < 4; b++) {
        int j = jg + 16 * b;
        float bias = 0.5f * (blf[j] + blb[j]);
#pragma unroll
        for (int a = 0; a < 4; a++) {
            int grow = base + ng + 16 * a;
            if (grow < n) {
                float v = 0.5f * acc[a][b] + bias;
                v = v > 0.f ? v : 0.f;
                OutB[(size_t)grow * 64 + j] = f2bf(v);
            }
        }
    }
}

// ---- pooling: sorted batch -> register accumulate, flush on graph change ---
__global__ __launch_bounds__(256) void pool_partial(const ushort* __restrict__ H,
                                                    const int* __restrict__ batch,
                                                    float* __restrict__ psum,
                                                    float* __restrict__ pcnt, int n) {
    __shared__ float ls[GG * 64];
    __shared__ float lc[GG];
    int t = threadIdx.x;
    for (int i = t; i < GG * 64; i += 256) ls[i] = 0.f;
    for (int i = t; i < GG; i += 256) lc[i] = 0.f;
    __syncthreads();
    int chunk = (n + gridDim.x - 1) / gridDim.x;
    int base = blockIdx.x * chunk;
    int end = base + chunk; if (end > n) end = n;
    int f = t & 63, r = t >> 6;
    float acc = 0.f; int cnt = 0; int curg = -1;
    for (int node = base + r; node < end; node += 4) {
        int g = batch[node];
        if (g != curg) {
            if (curg >= 0) {
                atomicAdd(&ls[curg * 64 + f], acc);
                if (f == 0) atomicAdd(&lc[curg], (float)cnt);
            }
            curg = g; acc = 0.f; cnt = 0;
        }
        acc += bf2f(H[(size_t)node * 64 + f]);
        cnt++;
    }
    if (curg >= 0) {
        atomicAdd(&ls[curg * 64 + f], acc);
        if (f == 0) atomicAdd(&lc[curg], (float)cnt);
    }
    __syncthreads();
    for (int i = t; i < GG * 64; i += 256) {
        float v = ls[i];
        if (v != 0.f) atomicAdd(&psum[i], v);
    }
    for (int i = t; i < GG; i += 256) {
        float v = lc[i];
        if (v != 0.f) atomicAdd(&pcnt[i], v);
    }
}

// ---------------- head ----------------
__global__ __launch_bounds__(256) void pool_final(const float* __restrict__ psum,
                                                  const float* __restrict__ pcnt,
                                                  const float* __restrict__ PW,
                                                  const float* __restrict__ Pb,
                                                  float* __restrict__ out) {
    int t = blockIdx.x * 256 + threadIdx.x;
    int g = t >> 4, o = t & 15;
    if (g >= GG) return;
    float inv = 1.f / fmaxf(pcnt[g], 1.f);
    float acc = 0.f;
#pragma unroll 8
    for (int k = 0; k < 64; k++) acc += psum[g * 64 + k] * PW[o * 64 + k];
    out[t] = acc * inv + Pb[o];
}

extern "C" void kernel_launch(void* const* d_in, const int* in_sizes, int n_in,
                              void* d_out, int out_size, void* d_ws, size_t ws_size,
                              hipStream_t stream) {
    const float* x      = (const float*)d_in[0];
    const int*   ei     = (const int*)d_in[1];
    const int*   batch  = (const int*)d_in[2];
    const float* l0f_Wl = (const float*)d_in[4];
    const float* l0f_bl = (const float*)d_in[5];
    const float* l0f_Wr = (const float*)d_in[6];
    const float* l0b_Wl = (const float*)d_in[7];
    const float* l0b_bl = (const float*)d_in[8];
    const float* l0b_Wr = (const float*)d_in[9];
    const float* l1f_Wl = (const float*)d_in[10];
    const float* l1f_bl = (const float*)d_in[11];
    const float* l1f_Wr = (const float*)d_in[12];
    const float* l1b_Wl = (const float*)d_in[13];
    const float* l1b_bl = (const float*)d_in[14];
    const float* l1b_Wr = (const float*)d_in[15];
    const float* pred_W = (const float*)d_in[16];
    const float* pred_b = (const float*)d_in[17];

    const int n = in_sizes[0] / 64;
    const int e = in_sizes[1] / 2;
    const size_t N64 = (size_t)n * 64;
    const int nb = (n + 255) / 256;

    // ---- workspace layout (int elements) ----
    int* ws = (int*)d_ws;
    size_t o = 0;
    int*   degfR = ws + o;  o += 4 * (size_t)n;          // zeroed
    int*   degbR = ws + o;  o += 4 * (size_t)n;          // zeroed
    float* psum  = (float*)(ws + o); o += GG * 64;       // zeroed
    float* pcnt  = (float*)(ws + o); o += GG;            // zeroed
    size_t zcount = o;
    int*   degf  = ws + o;  o += n;
    int*   degb  = ws + o;  o += n;
    int*   off_f = ws + o;  o += n + 1;
    int*   off_b = ws + o;  o += n + 1;
    o = (o + 3) & ~(size_t)3;
    int4*  baseF = (int4*)(ws + o); o += 4 * (size_t)n;
    int4*  baseB = (int4*)(ws + o); o += 4 * (size_t)n;
    int*   rankf = ws + o;  o += e;
    int*   rankb = ws + o;  o += e;
    int*   csr_f = ws + o;  o += e;
    int*   csr_b = ws + o;  o += e;
    int*   part_f = ws + o; o += 512;
    int*   part_b = ws + o; o += 512;
    float* invf  = (float*)(ws + o); o += n;
    float* invb  = (float*)(ws + o); o += n;
    o = (o + 3) & ~(size_t)3;
    float* aggf  = (float*)(ws + o); o += N64;             // [n][64] f32
    float* aggb  = (float*)(ws + o); o += N64;             // [n][64] f32
    ushort* xb   = (ushort*)(ws + o); o += (size_t)n * 32; // [n][64] bf16 (x->h0->h1)

    hipMemsetAsync(ws, 0, zcount * sizeof(int), stream);

    // CSR build (once; reused by both layers)
    if ((e & 3) == 0) {
        deg_rank4<<<(e / 4 + 255) / 256, 256, 0, stream>>>(ei, degfR, degbR,
                                                           rankf, rankb, e / 4, e, n);
    } else {
        deg_rank1<<<(e + 255) / 256, 256, 0, stream>>>(ei, degfR, degbR,
                                                       rankf, rankb, e, n);
    }
    to_bf16<<<((size_t)n * 16 + 255) / 256, 256, 0, stream>>>(x, xb, n * 16);
    sum_reps<<<nb, 256, 0, stream>>>(degfR, degbR, degf, degb, n);
    scan1<<<dim3(nb, 2), 256, 0, stream>>>(degf, degb, part_f, part_b, n);
    scan2<<<2, 512, 0, stream>>>(part_f, part_b, nb);
    scan3<<<dim3(nb, 2), 256, 0, stream>>>(degf, degb, part_f, part_b,
                                           off_f, off_b, invf, invb, n, e);
    make_base<<<nb, 256, 0, stream>>>(degfR, degbR, off_f, off_b, baseF, baseB, n);
    if ((e & 3) == 0) {
        fill_csr4<<<(e / 4 + 255) / 256, 256, 0, stream>>>(ei, baseF, baseB,
                                                           rankf, rankb, csr_f, csr_b,
                                                           e / 4, e);
    } else {
        fill_csr1<<<(e + 255) / 256, 256, 0, stream>>>(ei, baseF, baseB,
                                                       rankf, rankb, csr_f, csr_b, e);
    }

    // layer 0: gather bf16(x) -> f32 agg; sage -> h0 bf16 (in place in xb)
    gather_mean_bf<<<((size_t)n * 32 + 255) / 256, 256, 0, stream>>>(
        xb, off_f, csr_f, invf, off_b, csr_b, invb, aggf, aggb, n);
    fused_sage<<<(n + 63) / 64, 256, 0, stream>>>(xb, aggf, aggb,
        l0f_Wl, l0f_bl, l0f_Wr, l0b_Wl, l0b_bl, l0b_Wr, xb, n);

    // layer 1: gather bf16(h0) -> f32 agg; sage -> h1 bf16 (in place in xb)
    gather_mean_bf<<<((size_t)n * 32 + 255) / 256, 256, 0, stream>>>(
        xb, off_f, csr_f, invf, off_b, csr_b, invb, aggf, aggb, n);
    fused_sage<<<(n + 63) / 64, 256, 0, stream>>>(xb, aggf, aggb,
        l1f_Wl, l1f_bl, l1f_Wr, l1b_Wl, l1b_bl, l1b_Wr, xb, n);

    // pooling + head
    pool_partial<<<256, 256, 0, stream>>>(xb, batch, psum, pcnt, n);
    pool_final<<<8, 256, 0, stream>>>(psum, pcnt, pred_W, pred_b, (float*)d_out);
}

// Round 8
// 341.955 us; speedup vs baseline: 3.0829x; 1.2372x over previous
//
#include <hip/hip_runtime.h>
#include <hip/hip_bf16.h>

#define GG 128      // num_graphs (static in problem)
#define BSHIFT 9    // 512 nodes per bucket
#define BMASK 511
#define BNODES 512
#define PADI 16     // ints per padded global bucket counter (one 64B line each)
#define CAP 8192    // bucket capacity (mean ~5100 at n=100k,e=1M; +20 sigma margin)

// ---------------- bf16 helpers (RNE) ----------------
__device__ __forceinline__ ushort f2bf(float f) {
    union { float f; unsigned u; } v; v.f = f;
    unsigned r = v.u + 0x7FFF + ((v.u >> 16) & 1);
    return (ushort)(r >> 16);
}
__device__ __forceinline__ float bf2f(ushort s) {
    union { unsigned u; float f; } v; v.u = ((unsigned)s) << 16;
    return v.f;
}

// ---------------- f32 -> bf16 convert (vectorized) ----------------
__global__ __launch_bounds__(256) void to_bf16(const float* __restrict__ X,
                                               ushort* __restrict__ Xb, int n4) {
    int i = blockIdx.x * 256 + threadIdx.x;
    if (i >= n4) return;
    float4 v = reinterpret_cast<const float4*>(X)[i];
    ushort4 o;
    o.x = f2bf(v.x); o.y = f2bf(v.y); o.z = f2bf(v.z); o.w = f2bf(v.w);
    reinterpret_cast<ushort4*>(Xb)[i] = o;
}

// ------- phase A: bucket edges by coarse key (both directions) --------------
// Per block: LDS histogram -> per-edge local rank (LDS returning atomics),
// one global returning atomic per (block,bucket) on line-padded counters,
// then scatter int2(value,key) into fixed-CAP bucket regions (block's slots
// within a bucket are contiguous -> good write combining).
__global__ __launch_bounds__(256) void bucket_scatter(
    const int* __restrict__ ei,
    int* __restrict__ gcurF, int* __restrict__ gcurB,
    int2* __restrict__ bktF, int2* __restrict__ bktB,
    int e, int nb) {
    extern __shared__ int lds[];             // cntF[nb], cntB[nb]
    int* cntF = lds;
    int* cntB = lds + nb;
    int t = threadIdx.x;
    for (int i = t; i < 2 * nb; i += 256) lds[i] = 0;
    __syncthreads();
    int base = blockIdx.x * 2048;
    int s[8], d[8], rf[8], rb[8];
#pragma unroll
    for (int k = 0; k < 8; k++) {
        int idx = base + k * 256 + t;
        if (idx < e) {
            s[k] = ei[idx];
            d[k] = ei[e + idx];
            rf[k] = atomicAdd(&cntF[d[k] >> BSHIFT], 1);
            rb[k] = atomicAdd(&cntB[s[k] >> BSHIFT], 1);
        }
    }
    __syncthreads();
    for (int c = t; c < nb; c += 256) {
        int vF = cntF[c];
        if (vF) cntF[c] = atomicAdd(&gcurF[(size_t)c * PADI], vF);
        int vB = cntB[c];
        if (vB) cntB[c] = atomicAdd(&gcurB[(size_t)c * PADI], vB);
    }
    __syncthreads();
#pragma unroll
    for (int k = 0; k < 8; k++) {
        int idx = base + k * 256 + t;
        if (idx < e) {
            int cF = d[k] >> BSHIFT;
            int slotF = cntF[cF] + rf[k];
            if (slotF < CAP) bktF[(size_t)cF * CAP + slotF] = make_int2(s[k], d[k]);
            int cB = s[k] >> BSHIFT;
            int slotB = cntB[cB] + rb[k];
            if (slotB < CAP) bktB[(size_t)cB * CAP + slotB] = make_int2(d[k], s[k]);
        }
    }
}

// ------- scan bucket sizes -> bucket bases (nb <= 256; n <= 131072) ---------
__global__ __launch_bounds__(256) void bucket_scan(
    const int* __restrict__ gcurF, const int* __restrict__ gcurB,
    int* __restrict__ gbaseF, int* __restrict__ gbaseB,
    int* __restrict__ off_f, int* __restrict__ off_b,
    int nb, int n, int e) {
    const int* gcur = blockIdx.x ? gcurB : gcurF;
    int* gbase = blockIdx.x ? gbaseB : gbaseF;
    int* off = blockIdx.x ? off_b : off_f;
    __shared__ int sc[2][256];
    int t = threadIdx.x;
    int v = (t < nb) ? min(gcur[(size_t)t * PADI], CAP) : 0;
    sc[0][t] = v;
    __syncthreads();
    int pp = 0;
    for (int ofs = 1; ofs < 256; ofs <<= 1) {
        int u = sc[pp][t];
        if (t >= ofs) u += sc[pp][t - ofs];
        sc[pp ^ 1][t] = u;
        __syncthreads();
        pp ^= 1;
    }
    if (t < nb) gbase[t] = sc[pp][t] - v;    // exclusive
    if (t == 0) { gbase[nb] = e; off[n] = e; }
}

// ------- phase B: per-bucket CSR finalize (one block per bucket) ------------
// Two sweeps over the bucket's edges (LLC-hot): histogram 512 node counters,
// LDS scan -> off/inv, then place via LDS cursor atomics; csr writes are
// contiguous within the bucket region.
__global__ __launch_bounds__(256) void bucket_csr(
    const int2* __restrict__ bkt, const int* __restrict__ gcur,
    const int* __restrict__ gbase,
    int* __restrict__ csr, int* __restrict__ off, float* __restrict__ inv,
    int n, int nb) {
    __shared__ int cnt[BNODES];
    __shared__ int cur[BNODES];
    __shared__ int sc[2][BNODES];
    int c = blockIdx.x;
    int t = threadIdx.x;
    int size = gcur[(size_t)c * PADI];
    if (size > CAP) size = CAP;
    const int2* src = bkt + (size_t)c * CAP;
    for (int l = t; l < BNODES; l += 256) cnt[l] = 0;
    __syncthreads();
    for (int i = t; i < size; i += 256)
        atomicAdd(&cnt[src[i].y & BMASK], 1);
    __syncthreads();
    for (int l = t; l < BNODES; l += 256) sc[0][l] = cnt[l];
    __syncthreads();
    int pp = 0;
    for (int ofs = 1; ofs < BNODES; ofs <<= 1) {
        for (int l = t; l < BNODES; l += 256) {
            int u = sc[pp][l];
            if (l >= ofs) u += sc[pp][l - ofs];
            sc[pp ^ 1][l] = u;
        }
        __syncthreads();
        pp ^= 1;
    }
    int gb = gbase[c];
    for (int l = t; l < BNODES; l += 256) {
        int excl = sc[pp][l] - cnt[l];
        cur[l] = excl;
        int node = c * BNODES + l;
        if (node < n) {
            off[node] = gb + excl;
            inv[node] = 1.f / fmaxf((float)cnt[l], 1.f);
        }
    }
    __syncthreads();
    for (int i = t; i < size; i += 256) {
        int2 vk = src[i];
        int slot = atomicAdd(&cur[vk.y & BMASK], 1);
        csr[gb + slot] = vk.x;
    }
}

// ---- gather-mean: bf16 reads, f32 accumulate, bf16 agg writes --------------
__global__ __launch_bounds__(256) void gather_mean_bf(
    const ushort* __restrict__ Xb,
    const int* __restrict__ off_f, const int* __restrict__ csr_f,
    const float* __restrict__ invf,
    const int* __restrict__ off_b, const int* __restrict__ csr_b,
    const float* __restrict__ invb,
    ushort* __restrict__ aggf, ushort* __restrict__ aggb, int n) {
    int tid = blockIdx.x * 256 + threadIdx.x;
    int node = tid >> 5;
    if (node >= n) return;
    int dir = (tid >> 4) & 1;
    int c = (tid & 15) * 4;
    const int* off = dir ? off_b : off_f;
    const int* csr = dir ? csr_b : csr_f;
    const float* inv = dir ? invb : invf;
    ushort* agg = dir ? aggb : aggf;

    int b = off[node], en = off[node + 1];
    float ax = 0.f, ay = 0.f, az = 0.f, aw = 0.f;
    int k = b;
    for (; k + 3 < en; k += 4) {
        int n0 = csr[k], n1 = csr[k + 1], n2 = csr[k + 2], n3 = csr[k + 3];
        ushort4 v0 = *reinterpret_cast<const ushort4*>(Xb + (size_t)n0 * 64 + c);
        ushort4 v1 = *reinterpret_cast<const ushort4*>(Xb + (size_t)n1 * 64 + c);
        ushort4 v2 = *reinterpret_cast<const ushort4*>(Xb + (size_t)n2 * 64 + c);
        ushort4 v3 = *reinterpret_cast<const ushort4*>(Xb + (size_t)n3 * 64 + c);
        ax += bf2f(v0.x) + bf2f(v1.x) + bf2f(v2.x) + bf2f(v3.x);
        ay += bf2f(v0.y) + bf2f(v1.y) + bf2f(v2.y) + bf2f(v3.y);
        az += bf2f(v0.z) + bf2f(v1.z) + bf2f(v2.z) + bf2f(v3.z);
        aw += bf2f(v0.w) + bf2f(v1.w) + bf2f(v2.w) + bf2f(v3.w);
    }
    for (; k < en; k++) {
        int s = csr[k];
        ushort4 v = *reinterpret_cast<const ushort4*>(Xb + (size_t)s * 64 + c);
        ax += bf2f(v.x); ay += bf2f(v.y); az += bf2f(v.z); aw += bf2f(v.w);
    }
    float iv = inv[node];
    ushort4 r;
    r.x = f2bf(ax * iv); r.y = f2bf(ay * iv); r.z = f2bf(az * iv); r.w = f2bf(aw * iv);
    *reinterpret_cast<ushort4*>(agg + (size_t)node * 64 + c) = r;
}

// ---------------- fused bidirectional SAGE layer (all-bf16 tiles) -----------
// out_bf = relu(0.5*(mean_f@Wlf^T + mean_b@Wlb^T + xb@(Wrf+Wrb)^T + blf+blb))
__global__ __launch_bounds__(256) void fused_sage(
    const ushort* __restrict__ Xb,
    const ushort* __restrict__ aggf, const ushort* __restrict__ aggb,
    const float* __restrict__ Wlf, const float* __restrict__ blf,
    const float* __restrict__ Wrf,
    const float* __restrict__ Wlb, const float* __restrict__ blb,
    const float* __restrict__ Wrb,
    ushort* __restrict__ OutB, int n)
{
    __shared__ float sIn[64][68];
    __shared__ float sW[64][68];
    const int t = threadIdx.x;
    const int base = blockIdx.x * 64;
    const int jg = t & 15;
    const int ng = t >> 4;

    float acc[4][4];
#pragma unroll
    for (int a = 0; a < 4; a++)
#pragma unroll
        for (int b = 0; b < 4; b++) acc[a][b] = 0.f;

    for (int p = 0; p < 3; p++) {
        const ushort* src = (p == 0) ? aggf : (p == 1) ? aggb : Xb;
#pragma unroll
        for (int i = 0; i < 4; i++) {
            int f4 = t + 256 * i;
            int row = f4 >> 4, c4 = f4 & 15;
            int grow = base + row;
            float4 v = make_float4(0.f, 0.f, 0.f, 0.f);
            if (grow < n) {
                ushort4 u = *reinterpret_cast<const ushort4*>(src + (size_t)grow * 64 + c4 * 4);
                v = make_float4(bf2f(u.x), bf2f(u.y), bf2f(u.z), bf2f(u.w));
            }
            *reinterpret_cast<float4*>(&sIn[row][c4 * 4]) = v;
        }
#pragma unroll
        for (int i = 0; i < 4; i++) {
            int f4 = t + 256 * i;
            int row = f4 >> 4, c4 = f4 & 15;
            float4 w;
            if (p == 0) w = *reinterpret_cast<const float4*>(Wlf + row * 64 + c4 * 4);
            else if (p == 1) w = *reinterpret_cast<const float4*>(Wlb + row * 64 + c4 * 4);
            else {
                float4 w1 = *reinterpret_cast<const float4*>(Wrf + row * 64 + c4 * 4);
                float4 w2 = *reinterpret_cast<const float4*>(Wrb + row * 64 + c4 * 4);
                w = make_float4(w1.x + w2.x, w1.y + w2.y, w1.z + w2.z, w1.w + w2.w);
            }
            *reinterpret_cast<float4*>(&sW[row][c4 * 4]) = w;
        }
        __syncthreads();
        for (int kc = 0; kc < 16; kc++) {
            float4 av[4], wv[4];
#pragma unroll
            for (int i = 0; i < 4; i++)
                av[i] = *reinterpret_cast<const float4*>(&sIn[ng + 16 * i][kc * 4]);
#pragma unroll
            for (int i = 0; i < 4; i++)
                wv[i] = *reinterpret_cast<const float4*>(&sW[jg + 16 * i][kc * 4]);
#pragma unroll
            for (int a = 0; a < 4; a++)
#pragma unroll
                for (int b = 0; b < 4; b++)
                    acc[a][b] += av[a].x * wv[b].x + av[a].y * wv[b].y +
                                 av[a].z * wv[b].z + av[a].w * wv[b].w;
        }
        __syncthreads();
    }
#pragma unroll
    for (int b = 0; b < 4; b++) {
        int j = jg + 16 * b;
        float bias = 0.5f * (blf[j] + blb[j]);
#pragma unroll
        for (int a = 0; a < 4; a++) {
            int grow = base + ng + 16 * a;
            if (grow < n) {
                float v = 0.5f * acc[a][b] + bias;
                v = v > 0.f ? v : 0.f;
                OutB[(size_t)grow * 64 + j] = f2bf(v);
            }
        }
    }
}

// ---- pooling: sorted batch -> register accumulate, flush on graph change ---
__global__ __launch_bounds__(256) void pool_partial(const ushort* __restrict__ H,
                                                    const int* __restrict__ batch,
                                                    float* __restrict__ psum,
                                                    float* __restrict__ pcnt, int n) {
    __shared__ float ls[GG * 64];
    __shared__ float lc[GG];
    int t = threadIdx.x;
    for (int i = t; i < GG * 64; i += 256) ls[i] = 0.f;
    for (int i = t; i < GG; i += 256) lc[i] = 0.f;
    __syncthreads();
    int chunk = (n + gridDim.x - 1) / gridDim.x;
    int base = blockIdx.x * chunk;
    int end = base + chunk; if (end > n) end = n;
    int f = t & 63, r = t >> 6;
    float acc = 0.f; int cnt = 0; int curg = -1;
    for (int node = base + r; node < end; node += 4) {
        int g = batch[node];
        if (g != curg) {
            if (curg >= 0) {
                atomicAdd(&ls[curg * 64 + f], acc);
                if (f == 0) atomicAdd(&lc[curg], (float)cnt);
            }
            curg = g; acc = 0.f; cnt = 0;
        }
        acc += bf2f(H[(size_t)node * 64 + f]);
        cnt++;
    }
    if (curg >= 0) {
        atomicAdd(&ls[curg * 64 + f], acc);
        if (f == 0) atomicAdd(&lc[curg], (float)cnt);
    }
    __syncthreads();
    for (int i = t; i < GG * 64; i += 256) {
        float v = ls[i];
        if (v != 0.f) atomicAdd(&psum[i], v);
    }
    for (int i = t; i < GG; i += 256) {
        float v = lc[i];
        if (v != 0.f) atomicAdd(&pcnt[i], v);
    }
}

// ---------------- head ----------------
__global__ __launch_bounds__(256) void pool_final(const float* __restrict__ psum,
                                                  const float* __restrict__ pcnt,
                                                  const float* __restrict__ PW,
                                                  const float* __restrict__ Pb,
                                                  float* __restrict__ out) {
    int t = blockIdx.x * 256 + threadIdx.x;
    int g = t >> 4, o = t & 15;
    if (g >= GG) return;
    float inv = 1.f / fmaxf(pcnt[g], 1.f);
    float acc = 0.f;
#pragma unroll 8
    for (int k = 0; k < 64; k++) acc += psum[g * 64 + k] * PW[o * 64 + k];
    out[t] = acc * inv + Pb[o];
}

extern "C" void kernel_launch(void* const* d_in, const int* in_sizes, int n_in,
                              void* d_out, int out_size, void* d_ws, size_t ws_size,
                              hipStream_t stream) {
    const float* x      = (const float*)d_in[0];
    const int*   ei     = (const int*)d_in[1];
    const int*   batch  = (const int*)d_in[2];
    const float* l0f_Wl = (const float*)d_in[4];
    const float* l0f_bl = (const float*)d_in[5];
    const float* l0f_Wr = (const float*)d_in[6];
    const float* l0b_Wl = (const float*)d_in[7];
    const float* l0b_bl = (const float*)d_in[8];
    const float* l0b_Wr = (const float*)d_in[9];
    const float* l1f_Wl = (const float*)d_in[10];
    const float* l1f_bl = (const float*)d_in[11];
    const float* l1f_Wr = (const float*)d_in[12];
    const float* l1b_Wl = (const float*)d_in[13];
    const float* l1b_bl = (const float*)d_in[14];
    const float* l1b_Wr = (const float*)d_in[15];
    const float* pred_W = (const float*)d_in[16];
    const float* pred_b = (const float*)d_in[17];

    const int n = in_sizes[0] / 64;
    const int e = in_sizes[1] / 2;
    const int nb = (n + BNODES - 1) >> BSHIFT;   // <= 256 required (n <= 131072)

    // ---- workspace layout (int elements) ----
    int* ws = (int*)d_ws;
    size_t o = 0;
    int*   gcurF = ws + o;  o += (size_t)nb * PADI;      // zeroed
    int*   gcurB = ws + o;  o += (size_t)nb * PADI;      // zeroed
    float* psum  = (float*)(ws + o); o += GG * 64;       // zeroed
    float* pcnt  = (float*)(ws + o); o += GG;            // zeroed
    size_t zcount = o;
    int*   gbaseF = ws + o; o += nb + 1;
    int*   gbaseB = ws + o; o += nb + 1;
    int*   off_f = ws + o;  o += n + 1;
    int*   off_b = ws + o;  o += n + 1;
    float* invf  = (float*)(ws + o); o += n;
    float* invb  = (float*)(ws + o); o += n;
    int*   csr_f = ws + o;  o += e;
    int*   csr_b = ws + o;  o += e;
    o = (o + 3) & ~(size_t)3;
    int2*  bktF  = (int2*)(ws + o); o += 2 * (size_t)nb * CAP;
    int2*  bktB  = (int2*)(ws + o); o += 2 * (size_t)nb * CAP;
    ushort* xb    = (ushort*)(ws + o); o += (size_t)n * 32;  // [n][64] bf16 (x->h0->h1)
    ushort* aggfb = (ushort*)(ws + o); o += (size_t)n * 32;  // [n][64] bf16
    ushort* aggbb = (ushort*)(ws + o); o += (size_t)n * 32;  // [n][64] bf16

    hipMemsetAsync(ws, 0, zcount * sizeof(int), stream);

    // ---- CSR build via bucket counting-sort (no per-edge returning atomics) ----
    to_bf16<<<((size_t)n * 16 + 255) / 256, 256, 0, stream>>>(x, xb, n * 16);
    bucket_scatter<<<(e + 2047) / 2048, 256, 2 * nb * sizeof(int), stream>>>(
        ei, gcurF, gcurB, bktF, bktB, e, nb);
    bucket_scan<<<2, 256, 0, stream>>>(gcurF, gcurB, gbaseF, gbaseB,
                                       off_f, off_b, nb, n, e);
    bucket_csr<<<nb, 256, 0, stream>>>(bktF, gcurF, gbaseF, csr_f, off_f, invf, n, nb);
    bucket_csr<<<nb, 256, 0, stream>>>(bktB, gcurB, gbaseB, csr_b, off_b, invb, n, nb);

    // layer 0: gather bf16(x) -> bf16 agg; sage -> h0 bf16 (in place in xb)
    gather_mean_bf<<<((size_t)n * 32 + 255) / 256, 256, 0, stream>>>(
        xb, off_f, csr_f, invf, off_b, csr_b, invb, aggfb, aggbb, n);
    fused_sage<<<(n + 63) / 64, 256, 0, stream>>>(xb, aggfb, aggbb,
        l0f_Wl, l0f_bl, l0f_Wr, l0b_Wl, l0b_bl, l0b_Wr, xb, n);

    // layer 1: gather bf16(h0) -> bf16 agg; sage -> h1 bf16 (in place in xb)
    gather_mean_bf<<<((size_t)n * 32 + 255) / 256, 256, 0, stream>>>(
        xb, off_f, csr_f, invf, off_b, csr_b, invb, aggfb, aggbb, n);
    fused_sage<<<(n + 63) / 64, 256, 0, stream>>>(xb, aggfb, aggbb,
        l1f_Wl, l1f_bl, l1f_Wr, l1b_Wl, l1b_bl, l1b_Wr, xb, n);

    // pooling + head
    pool_partial<<<256, 256, 0, stream>>>(xb, batch, psum, pcnt, n);
    pool_final<<<8, 256, 0, stream>>>(psum, pcnt, pred_W, pred_b, (float*)d_out);
}

// Round 9
// 272.762 us; speedup vs baseline: 3.8649x; 1.2537x over previous
//
#include <hip/hip_runtime.h>
#include <hip/hip_bf16.h>

#define GG 128      // num_graphs (static in problem)
#define BSHIFT 9    // 512 nodes per bucket
#define BMASK 511
#define BNODES 512
#define PADI 16     // ints per padded global bucket counter (one 64B line each)
#define CAP 8192    // bucket capacity (mean ~5100 at n=100k,e=1M; +20 sigma margin)

typedef __attribute__((ext_vector_type(8))) short bf16x8;
typedef __attribute__((ext_vector_type(4))) float f32x4;

// ---------------- bf16 helpers (RNE) ----------------
__device__ __forceinline__ ushort f2bf(float f) {
    union { float f; unsigned u; } v; v.f = f;
    unsigned r = v.u + 0x7FFF + ((v.u >> 16) & 1);
    return (ushort)(r >> 16);
}
__device__ __forceinline__ float bf2f(ushort s) {
    union { unsigned u; float f; } v; v.u = ((unsigned)s) << 16;
    return v.f;
}

// ---------------- f32 -> bf16 convert (vectorized) ----------------
__global__ __launch_bounds__(256) void to_bf16(const float* __restrict__ X,
                                               ushort* __restrict__ Xb, int n4) {
    int i = blockIdx.x * 256 + threadIdx.x;
    if (i >= n4) return;
    float4 v = reinterpret_cast<const float4*>(X)[i];
    ushort4 o;
    o.x = f2bf(v.x); o.y = f2bf(v.y); o.z = f2bf(v.z); o.w = f2bf(v.w);
    reinterpret_cast<ushort4*>(Xb)[i] = o;
}

// ------- phase A: bucket edges by coarse key (both directions) --------------
__global__ __launch_bounds__(256) void bucket_scatter(
    const int* __restrict__ ei,
    int* __restrict__ gcurF, int* __restrict__ gcurB,
    int2* __restrict__ bktF, int2* __restrict__ bktB,
    int e, int nb) {
    extern __shared__ int lds[];             // cntF[nb], cntB[nb]
    int* cntF = lds;
    int* cntB = lds + nb;
    int t = threadIdx.x;
    for (int i = t; i < 2 * nb; i += 256) lds[i] = 0;
    __syncthreads();
    int base = blockIdx.x * 2048;
    int s[8], d[8], rf[8], rb[8];
#pragma unroll
    for (int k = 0; k < 8; k++) {
        int idx = base + k * 256 + t;
        if (idx < e) {
            s[k] = ei[idx];
            d[k] = ei[e + idx];
            rf[k] = atomicAdd(&cntF[d[k] >> BSHIFT], 1);
            rb[k] = atomicAdd(&cntB[s[k] >> BSHIFT], 1);
        }
    }
    __syncthreads();
    for (int c = t; c < nb; c += 256) {
        int vF = cntF[c];
        if (vF) cntF[c] = atomicAdd(&gcurF[(size_t)c * PADI], vF);
        int vB = cntB[c];
        if (vB) cntB[c] = atomicAdd(&gcurB[(size_t)c * PADI], vB);
    }
    __syncthreads();
#pragma unroll
    for (int k = 0; k < 8; k++) {
        int idx = base + k * 256 + t;
        if (idx < e) {
            int cF = d[k] >> BSHIFT;
            int slotF = cntF[cF] + rf[k];
            if (slotF < CAP) bktF[(size_t)cF * CAP + slotF] = make_int2(s[k], d[k]);
            int cB = s[k] >> BSHIFT;
            int slotB = cntB[cB] + rb[k];
            if (slotB < CAP) bktB[(size_t)cB * CAP + slotB] = make_int2(d[k], s[k]);
        }
    }
}

// ------- scan bucket sizes -> bucket bases (nb <= 256) ----------------------
__global__ __launch_bounds__(256) void bucket_scan(
    const int* __restrict__ gcurF, const int* __restrict__ gcurB,
    int* __restrict__ gbaseF, int* __restrict__ gbaseB,
    int* __restrict__ off_f, int* __restrict__ off_b,
    int nb, int n, int e) {
    const int* gcur = blockIdx.x ? gcurB : gcurF;
    int* gbase = blockIdx.x ? gbaseB : gbaseF;
    int* off = blockIdx.x ? off_b : off_f;
    __shared__ int sc[2][256];
    int t = threadIdx.x;
    int v = (t < nb) ? min(gcur[(size_t)t * PADI], CAP) : 0;
    sc[0][t] = v;
    __syncthreads();
    int pp = 0;
    for (int ofs = 1; ofs < 256; ofs <<= 1) {
        int u = sc[pp][t];
        if (t >= ofs) u += sc[pp][t - ofs];
        sc[pp ^ 1][t] = u;
        __syncthreads();
        pp ^= 1;
    }
    if (t < nb) gbase[t] = sc[pp][t] - v;    // exclusive
    if (t == 0) { gbase[nb] = e; off[n] = e; }
}

// ------- phase B: per-bucket CSR finalize (one block per bucket) ------------
__global__ __launch_bounds__(256) void bucket_csr(
    const int2* __restrict__ bkt, const int* __restrict__ gcur,
    const int* __restrict__ gbase,
    int* __restrict__ csr, int* __restrict__ off, float* __restrict__ inv,
    int n, int nb) {
    __shared__ int cnt[BNODES];
    __shared__ int cur[BNODES];
    __shared__ int sc[2][BNODES];
    int c = blockIdx.x;
    int t = threadIdx.x;
    int size = gcur[(size_t)c * PADI];
    if (size > CAP) size = CAP;
    const int2* src = bkt + (size_t)c * CAP;
    for (int l = t; l < BNODES; l += 256) cnt[l] = 0;
    __syncthreads();
    for (int i = t; i < size; i += 256)
        atomicAdd(&cnt[src[i].y & BMASK], 1);
    __syncthreads();
    for (int l = t; l < BNODES; l += 256) sc[0][l] = cnt[l];
    __syncthreads();
    int pp = 0;
    for (int ofs = 1; ofs < BNODES; ofs <<= 1) {
        for (int l = t; l < BNODES; l += 256) {
            int u = sc[pp][l];
            if (l >= ofs) u += sc[pp][l - ofs];
            sc[pp ^ 1][l] = u;
        }
        __syncthreads();
        pp ^= 1;
    }
    int gb = gbase[c];
    for (int l = t; l < BNODES; l += 256) {
        int excl = sc[pp][l] - cnt[l];
        cur[l] = excl;
        int node = c * BNODES + l;
        if (node < n) {
            off[node] = gb + excl;
            inv[node] = 1.f / fmaxf((float)cnt[l], 1.f);
        }
    }
    __syncthreads();
    for (int i = t; i < size; i += 256) {
        int2 vk = src[i];
        int slot = atomicAdd(&cur[vk.y & BMASK], 1);
        csr[gb + slot] = vk.x;
    }
}

// ---- gather-mean: bf16 reads, f32 accumulate, bf16 agg writes --------------
__global__ __launch_bounds__(256) void gather_mean_bf(
    const ushort* __restrict__ Xb,
    const int* __restrict__ off_f, const int* __restrict__ csr_f,
    const float* __restrict__ invf,
    const int* __restrict__ off_b, const int* __restrict__ csr_b,
    const float* __restrict__ invb,
    ushort* __restrict__ aggf, ushort* __restrict__ aggb, int n) {
    int tid = blockIdx.x * 256 + threadIdx.x;
    int node = tid >> 5;
    if (node >= n) return;
    int dir = (tid >> 4) & 1;
    int c = (tid & 15) * 4;
    const int* off = dir ? off_b : off_f;
    const int* csr = dir ? csr_b : csr_f;
    const float* inv = dir ? invb : invf;
    ushort* agg = dir ? aggb : aggf;

    int b = off[node], en = off[node + 1];
    float ax = 0.f, ay = 0.f, az = 0.f, aw = 0.f;
    int k = b;
    for (; k + 3 < en; k += 4) {
        int n0 = csr[k], n1 = csr[k + 1], n2 = csr[k + 2], n3 = csr[k + 3];
        ushort4 v0 = *reinterpret_cast<const ushort4*>(Xb + (size_t)n0 * 64 + c);
        ushort4 v1 = *reinterpret_cast<const ushort4*>(Xb + (size_t)n1 * 64 + c);
        ushort4 v2 = *reinterpret_cast<const ushort4*>(Xb + (size_t)n2 * 64 + c);
        ushort4 v3 = *reinterpret_cast<const ushort4*>(Xb + (size_t)n3 * 64 + c);
        ax += bf2f(v0.x) + bf2f(v1.x) + bf2f(v2.x) + bf2f(v3.x);
        ay += bf2f(v0.y) + bf2f(v1.y) + bf2f(v2.y) + bf2f(v3.y);
        az += bf2f(v0.z) + bf2f(v1.z) + bf2f(v2.z) + bf2f(v3.z);
        aw += bf2f(v0.w) + bf2f(v1.w) + bf2f(v2.w) + bf2f(v3.w);
    }
    for (; k < en; k++) {
        int s = csr[k];
        ushort4 v = *reinterpret_cast<const ushort4*>(Xb + (size_t)s * 64 + c);
        ax += bf2f(v.x); ay += bf2f(v.y); az += bf2f(v.z); aw += bf2f(v.w);
    }
    float iv = inv[node];
    ushort4 r;
    r.x = f2bf(ax * iv); r.y = f2bf(ay * iv); r.z = f2bf(az * iv); r.w = f2bf(aw * iv);
    *reinterpret_cast<ushort4*>(agg + (size_t)node * 64 + c) = r;
}

// ---------------- fused bidirectional SAGE layer (MFMA bf16) ----------------
// out_bf = relu(0.5*(aggf@Wlf^T + aggb@Wlb^T + xb@(Wrf+Wrb)^T) + 0.5*(blf+blb))
// Block: 64 nodes x 64 outs, 4 waves (wave = 16 rows x 64 cols), K=192.
// Fragment layouts (m89-verified family):
//   A[m][k]: m=lane&15, k=(lane>>4)*8+j   B[k][j]: k=(lane>>4)*8+j, j=lane&15
//   D[m][j]: m=(lane>>4)*4+reg, j=lane&15
__global__ __launch_bounds__(256) void fused_sage_mfma(
    const ushort* __restrict__ Xb,
    const ushort* __restrict__ aggf, const ushort* __restrict__ aggb,
    const float* __restrict__ Wlf, const float* __restrict__ blf,
    const float* __restrict__ Wrf,
    const float* __restrict__ Wlb, const float* __restrict__ blb,
    const float* __restrict__ Wrb,
    ushort* __restrict__ OutB, int n)
{
    __shared__ ushort sA[64][72];       // +8 bf16 pad: 144B stride -> 4-bank step
    __shared__ ushort sW[3][64][72];    // bf16 weights, W[j][k] layout
    __shared__ float  sBias[64];
    const int t = threadIdx.x;
    const int base = blockIdx.x * 64;
    const int lane = t & 63;
    const int m0 = (t >> 6) * 16;       // wave's row offset
    const int lr = lane & 15;           // A row / B col / D col
    const int kb = lane >> 4;           // k-block 0..3

    // ---- stage weights (bf16) + bias, once ----
#pragma unroll
    for (int i = 0; i < 4; i++) {
        int idx4 = t + 256 * i;               // 1024 float4s = 64x64
        int row = idx4 >> 4, c4 = idx4 & 15;
        float4 w0 = *reinterpret_cast<const float4*>(Wlf + row * 64 + c4 * 4);
        float4 w1 = *reinterpret_cast<const float4*>(Wlb + row * 64 + c4 * 4);
        float4 wa = *reinterpret_cast<const float4*>(Wrf + row * 64 + c4 * 4);
        float4 wb = *reinterpret_cast<const float4*>(Wrb + row * 64 + c4 * 4);
        ushort4 o;
        o.x = f2bf(w0.x); o.y = f2bf(w0.y); o.z = f2bf(w0.z); o.w = f2bf(w0.w);
        *reinterpret_cast<ushort4*>(&sW[0][row][c4 * 4]) = o;
        o.x = f2bf(w1.x); o.y = f2bf(w1.y); o.z = f2bf(w1.z); o.w = f2bf(w1.w);
        *reinterpret_cast<ushort4*>(&sW[1][row][c4 * 4]) = o;
        o.x = f2bf(wa.x + wb.x); o.y = f2bf(wa.y + wb.y);
        o.z = f2bf(wa.z + wb.z); o.w = f2bf(wa.w + wb.w);
        *reinterpret_cast<ushort4*>(&sW[2][row][c4 * 4]) = o;
    }
    if (t < 64) sBias[t] = 0.5f * (blf[t] + blb[t]);

    f32x4 acc0 = {0.f, 0.f, 0.f, 0.f};
    f32x4 acc1 = {0.f, 0.f, 0.f, 0.f};
    f32x4 acc2 = {0.f, 0.f, 0.f, 0.f};
    f32x4 acc3 = {0.f, 0.f, 0.f, 0.f};

    for (int p = 0; p < 3; p++) {
        const ushort* src = (p == 0) ? aggf : (p == 1) ? aggb : Xb;
        __syncthreads();   // protect sA from previous pass readers (and sW stage)
        // ---- stage A tile: 64 rows x 64 bf16, 16B per thread x2 ----
#pragma unroll
        for (int i = 0; i < 2; i++) {
            int c8 = t + 256 * i;             // 512 chunks of 8 bf16
            int row = c8 >> 3, k8 = (c8 & 7) * 8;
            int node = base + row;
            uint4 v = make_uint4(0u, 0u, 0u, 0u);
            if (node < n)
                v = *reinterpret_cast<const uint4*>(src + (size_t)node * 64 + k8);
            *reinterpret_cast<uint4*>(&sA[row][k8]) = v;
        }
        __syncthreads();
        // ---- MFMA: 2 k-halves x 4 col-blocks ----
#pragma unroll
        for (int kh = 0; kh < 2; kh++) {
            bf16x8 a = *(const bf16x8*)(&sA[m0 + lr][kh * 32 + kb * 8]);
            bf16x8 b0 = *(const bf16x8*)(&sW[p][0 * 16 + lr][kh * 32 + kb * 8]);
            bf16x8 b1 = *(const bf16x8*)(&sW[p][1 * 16 + lr][kh * 32 + kb * 8]);
            bf16x8 b2 = *(const bf16x8*)(&sW[p][2 * 16 + lr][kh * 32 + kb * 8]);
            bf16x8 b3 = *(const bf16x8*)(&sW[p][3 * 16 + lr][kh * 32 + kb * 8]);
            acc0 = __builtin_amdgcn_mfma_f32_16x16x32_bf16(a, b0, acc0, 0, 0, 0);
            acc1 = __builtin_amdgcn_mfma_f32_16x16x32_bf16(a, b1, acc1, 0, 0, 0);
            acc2 = __builtin_amdgcn_mfma_f32_16x16x32_bf16(a, b2, acc2, 0, 0, 0);
            acc3 = __builtin_amdgcn_mfma_f32_16x16x32_bf16(a, b3, acc3, 0, 0, 0);
        }
    }
    // ---- epilogue: bias + relu + bf16 store ----
    // D: row m = m0 + kb*4 + i, col j = lr + 16*b
#pragma unroll
    for (int b = 0; b < 4; b++) {
        int j = lr + 16 * b;
        float bias = sBias[j];
        f32x4 ac = (b == 0) ? acc0 : (b == 1) ? acc1 : (b == 2) ? acc2 : acc3;
#pragma unroll
        for (int i = 0; i < 4; i++) {
            int row = base + m0 + kb * 4 + i;
            if (row < n) {
                float v = 0.5f * ac[i] + bias;
                v = v > 0.f ? v : 0.f;
                OutB[(size_t)row * 64 + j] = f2bf(v);
            }
        }
    }
}

// ---- pooling: sorted batch -> register accumulate, flush on graph change ---
__global__ __launch_bounds__(256) void pool_partial(const ushort* __restrict__ H,
                                                    const int* __restrict__ batch,
                                                    float* __restrict__ psum,
                                                    float* __restrict__ pcnt, int n) {
    __shared__ float ls[GG * 64];
    __shared__ float lc[GG];
    int t = threadIdx.x;
    for (int i = t; i < GG * 64; i += 256) ls[i] = 0.f;
    for (int i = t; i < GG; i += 256) lc[i] = 0.f;
    __syncthreads();
    int chunk = (n + gridDim.x - 1) / gridDim.x;
    int base = blockIdx.x * chunk;
    int end = base + chunk; if (end > n) end = n;
    int f = t & 63, r = t >> 6;
    float acc = 0.f; int cnt = 0; int curg = -1;
    for (int node = base + r; node < end; node += 4) {
        int g = batch[node];
        if (g != curg) {
            if (curg >= 0) {
                atomicAdd(&ls[curg * 64 + f], acc);
                if (f == 0) atomicAdd(&lc[curg], (float)cnt);
            }
            curg = g; acc = 0.f; cnt = 0;
        }
        acc += bf2f(H[(size_t)node * 64 + f]);
        cnt++;
    }
    if (curg >= 0) {
        atomicAdd(&ls[curg * 64 + f], acc);
        if (f == 0) atomicAdd(&lc[curg], (float)cnt);
    }
    __syncthreads();
    for (int i = t; i < GG * 64; i += 256) {
        float v = ls[i];
        if (v != 0.f) atomicAdd(&psum[i], v);
    }
    for (int i = t; i < GG; i += 256) {
        float v = lc[i];
        if (v != 0.f) atomicAdd(&pcnt[i], v);
    }
}

// ---------------- head ----------------
__global__ __launch_bounds__(256) void pool_final(const float* __restrict__ psum,
                                                  const float* __restrict__ pcnt,
                                                  const float* __restrict__ PW,
                                                  const float* __restrict__ Pb,
                                                  float* __restrict__ out) {
    int t = blockIdx.x * 256 + threadIdx.x;
    int g = t >> 4, o = t & 15;
    if (g >= GG) return;
    float inv = 1.f / fmaxf(pcnt[g], 1.f);
    float acc = 0.f;
#pragma unroll 8
    for (int k = 0; k < 64; k++) acc += psum[g * 64 + k] * PW[o * 64 + k];
    out[t] = acc * inv + Pb[o];
}

extern "C" void kernel_launch(void* const* d_in, const int* in_sizes, int n_in,
                              void* d_out, int out_size, void* d_ws, size_t ws_size,
                              hipStream_t stream) {
    const float* x      = (const float*)d_in[0];
    const int*   ei     = (const int*)d_in[1];
    const int*   batch  = (const int*)d_in[2];
    const float* l0f_Wl = (const float*)d_in[4];
    const float* l0f_bl = (const float*)d_in[5];
    const float* l0f_Wr = (const float*)d_in[6];
    const float* l0b_Wl = (const float*)d_in[7];
    const float* l0b_bl = (const float*)d_in[8];
    const float* l0b_Wr = (const float*)d_in[9];
    const float* l1f_Wl = (const float*)d_in[10];
    const float* l1f_bl = (const float*)d_in[11];
    const float* l1f_Wr = (const float*)d_in[12];
    const float* l1b_Wl = (const float*)d_in[13];
    const float* l1b_bl = (const float*)d_in[14];
    const float* l1b_Wr = (const float*)d_in[15];
    const float* pred_W = (const float*)d_in[16];
    const float* pred_b = (const float*)d_in[17];

    const int n = in_sizes[0] / 64;
    const int e = in_sizes[1] / 2;
    const int nb = (n + BNODES - 1) >> BSHIFT;   // <= 256 required

    // ---- workspace layout (int elements) ----
    int* ws = (int*)d_ws;
    size_t o = 0;
    int*   gcurF = ws + o;  o += (size_t)nb * PADI;      // zeroed
    int*   gcurB = ws + o;  o += (size_t)nb * PADI;      // zeroed
    float* psum  = (float*)(ws + o); o += GG * 64;       // zeroed
    float* pcnt  = (float*)(ws + o); o += GG;            // zeroed
    size_t zcount = o;
    int*   gbaseF = ws + o; o += nb + 1;
    int*   gbaseB = ws + o; o += nb + 1;
    int*   off_f = ws + o;  o += n + 1;
    int*   off_b = ws + o;  o += n + 1;
    float* invf  = (float*)(ws + o); o += n;
    float* invb  = (float*)(ws + o); o += n;
    int*   csr_f = ws + o;  o += e;
    int*   csr_b = ws + o;  o += e;
    o = (o + 3) & ~(size_t)3;
    int2*  bktF  = (int2*)(ws + o); o += 2 * (size_t)nb * CAP;
    int2*  bktB  = (int2*)(ws + o); o += 2 * (size_t)nb * CAP;
    ushort* xb    = (ushort*)(ws + o); o += (size_t)n * 32;  // [n][64] bf16 (x->h0->h1)
    ushort* aggfb = (ushort*)(ws + o); o += (size_t)n * 32;  // [n][64] bf16
    ushort* aggbb = (ushort*)(ws + o); o += (size_t)n * 32;  // [n][64] bf16

    hipMemsetAsync(ws, 0, zcount * sizeof(int), stream);

    // ---- CSR build via bucket counting-sort ----
    to_bf16<<<((size_t)n * 16 + 255) / 256, 256, 0, stream>>>(x, xb, n * 16);
    bucket_scatter<<<(e + 2047) / 2048, 256, 2 * nb * sizeof(int), stream>>>(
        ei, gcurF, gcurB, bktF, bktB, e, nb);
    bucket_scan<<<2, 256, 0, stream>>>(gcurF, gcurB, gbaseF, gbaseB,
                                       off_f, off_b, nb, n, e);
    bucket_csr<<<nb, 256, 0, stream>>>(bktF, gcurF, gbaseF, csr_f, off_f, invf, n, nb);
    bucket_csr<<<nb, 256, 0, stream>>>(bktB, gcurB, gbaseB, csr_b, off_b, invb, n, nb);

    // layer 0: gather bf16(x) -> bf16 agg; MFMA sage -> h0 bf16 (in place)
    gather_mean_bf<<<((size_t)n * 32 + 255) / 256, 256, 0, stream>>>(
        xb, off_f, csr_f, invf, off_b, csr_b, invb, aggfb, aggbb, n);
    fused_sage_mfma<<<(n + 63) / 64, 256, 0, stream>>>(xb, aggfb, aggbb,
        l0f_Wl, l0f_bl, l0f_Wr, l0b_Wl, l0b_bl, l0b_Wr, xb, n);

    // layer 1: gather bf16(h0) -> bf16 agg; MFMA sage -> h1 bf16 (in place)
    gather_mean_bf<<<((size_t)n * 32 + 255) / 256, 256, 0, stream>>>(
        xb, off_f, csr_f, invf, off_b, csr_b, invb, aggfb, aggbb, n);
    fused_sage_mfma<<<(n + 63) / 64, 256, 0, stream>>>(xb, aggfb, aggbb,
        l1f_Wl, l1f_bl, l1f_Wr, l1b_Wl, l1b_bl, l1b_Wr, xb, n);

    // pooling + head
    pool_partial<<<256, 256, 0, stream>>>(xb, batch, psum, pcnt, n);
    pool_final<<<8, 256, 0, stream>>>(psum, pcnt, pred_W, pred_b, (float*)d_out);
}